// Round 6
// baseline (136.806 us; speedup 1.0000x reference)
//
#include <hip/hip_runtime.h>
#include <hip/hip_bf16.h>

typedef __bf16 bf16x8 __attribute__((ext_vector_type(8)));
typedef float f32x4 __attribute__((ext_vector_type(4)));

#define NB 32
#define CIN 512
#define COUT 128
#define NP 3136   // 56*56
#define WIMG 56

__device__ __forceinline__ unsigned fenc(float f) {
    unsigned u = __float_as_uint(f);
    return (u & 0x80000000u) ? ~u : (u | 0x80000000u);
}
__device__ __forceinline__ float fdec(unsigned e) {
    unsigned u = (e & 0x80000000u) ? (e ^ 0x80000000u) : ~e;
    return __uint_as_float(u);
}
__device__ __forceinline__ float bflo(unsigned u) { return __uint_as_float(u << 16); }
__device__ __forceinline__ float bfhi(unsigned u) { return __uint_as_float(u & 0xffff0000u); }

// Relaxed barrier: LDS-visibility only, no vmcnt drain (keep prefetch in flight).
__device__ __forceinline__ void lds_barrier() {
    asm volatile("s_waitcnt lgkmcnt(0)" ::: "memory");
    __builtin_amdgcn_s_barrier();
    __builtin_amdgcn_sched_barrier(0);
}

// ---------------------------------------------------------------------------
// Kernel 0: W f32 -> bf16, plus zero-init of sumh/mxenc.
// ---------------------------------------------------------------------------
__global__ __launch_bounds__(256) void k_wcvt(const float* __restrict__ wp,
                                              ushort* __restrict__ wb,
                                              unsigned* __restrict__ zero8k)
{
    int i = blockIdx.x * 256 + threadIdx.x;   // 16384 threads, 4 elems each
    if (i < 2 * NB * COUT) zero8k[i] = 0u;
    float4 f = *(const float4*)(wp + i * 4);
    ushort4 u;
    __bf16 b0 = (__bf16)f.x, b1 = (__bf16)f.y, b2 = (__bf16)f.z, b3 = (__bf16)f.w;
    u.x = *(ushort*)&b0; u.y = *(ushort*)&b1; u.z = *(ushort*)&b2; u.w = *(ushort*)&b3;
    *(ushort4*)(wb + i * 4) = u;
}

// ---------------------------------------------------------------------------
// Kernel 1: GEMM (W[128,512] @ X_b[512,3136]) + BN + SiLU, store h (bf16),
// accumulate per-(b,o) spatial sum and max. XCD-aware swizzle: XCD k owns
// images 4k..4k+3 (196 consecutive work-items).
// ---------------------------------------------------------------------------
__global__ __launch_bounds__(512, 4) void k_main(
    const float* __restrict__ x, const ushort* __restrict__ wb,
    const float* __restrict__ bn_g, const float* __restrict__ bn_b,
    const float* __restrict__ bn_m, const float* __restrict__ bn_v,
    ushort* __restrict__ hout, float* __restrict__ sumh, unsigned* __restrict__ mxenc)
{
    __shared__ __align__(16) ushort Xs[2][64 * 64];  // 8KB each
    __shared__ float bnss[256];

    const int bid  = blockIdx.x;                    // 0..1567, 1568 % 8 == 0
    const int swz  = (bid & 7) * 196 + (bid >> 3);  // bijective XCD swizzle
    const int t    = threadIdx.x;
    const int b    = swz / 49;
    const int p0   = (swz % 49) * 64;
    const int lane = t & 63;
    const int l15  = lane & 15;
    const int lg   = lane >> 4;     // 0..3
    const int w    = t >> 6;        // wave 0..7

    if (t < COUT) {
        float sc = bn_g[t] * rsqrtf(bn_v[t] + 1e-5f);
        bnss[t]        = sc;
        bnss[t + COUT] = bn_b[t] - bn_m[t] * sc;
    }

    // ---- A-fragments (W) for the whole K dimension: 16 x bf16x8 = 64 VGPR
    const ushort* wrow = wb + (w * 16 + l15) * CIN + lg * 8;
    bf16x8 af[16];
#pragma unroll
    for (int ks = 0; ks < 16; ++ks)
        af[ks] = *(const bf16x8*)(wrow + ks * 32);

    // ---- staging geometry: thread t stages row p=t&63, k-octet kg=w
    const int pr = t & 63;
    const int kg = w;
    const float* xb = x + ((size_t)b * CIN) * NP + p0 + pr;
    const int wbyte = pr * 128 + ((kg * 16) ^ ((pr & 7) << 4));

    f32x4 acc[4];
#pragma unroll
    for (int nf = 0; nf < 4; ++nf) acc[nf] = (f32x4){0.f, 0.f, 0.f, 0.f};

    float ld[2][8];

    // prologue: issue tiles 0 and 1; write tile 0 into buf 0
#pragma unroll
    for (int j = 0; j < 8; ++j) ld[0][j] = xb[(kg * 8 + j) * NP];
#pragma unroll
    for (int j = 0; j < 8; ++j) ld[1][j] = xb[(64 + kg * 8 + j) * NP];
    {
        bf16x8 v8;
#pragma unroll
        for (int j = 0; j < 8; ++j) v8[j] = (__bf16)ld[0][j];
        *(bf16x8*)((char*)Xs[0] + wbyte) = v8;
    }

#pragma unroll
    for (int kc = 0; kc < 8; ++kc) {
        lds_barrier();
        // issue tile kc+2 into the reg set freed by tile kc (distance-2 prefetch)
        if (kc < 6) {
#pragma unroll
            for (int j = 0; j < 8; ++j)
                ld[kc & 1][j] = xb[((kc + 2) * 64 + kg * 8 + j) * NP];
        }
        // compute current tile from Xs[kc&1]
#pragma unroll
        for (int ks = 0; ks < 2; ++ks) {
#pragma unroll
            for (int nf = 0; nf < 4; ++nf) {
                int row  = nf * 16 + l15;
                int byte = row * 128 + ((ks * 64 + lg * 16) ^ ((row & 7) << 4));
                bf16x8 bfr = *(const bf16x8*)((const char*)Xs[kc & 1] + byte);
                acc[nf] = __builtin_amdgcn_mfma_f32_16x16x32_bf16(
                    af[kc * 2 + ks], bfr, acc[nf], 0, 0, 0);
            }
        }
        // write-late: cvt + ds_write tile kc+1 (issued one iteration ago)
        if (kc < 7) {
            bf16x8 v8;
#pragma unroll
            for (int j = 0; j < 8; ++j) v8[j] = (__bf16)ld[(kc + 1) & 1][j];
            *(bf16x8*)((char*)Xs[(kc + 1) & 1] + wbyte) = v8;
        }
    }

    // ---- epilogue: BN + SiLU, store bf16 h, per-(b,o) sum/max
#pragma unroll
    for (int reg = 0; reg < 4; ++reg) {
        int o = w * 16 + lg * 4 + reg;
        float sc = bnss[o], sh = bnss[o + COUT];
        float s_ = 0.f, m_ = -1e30f;
#pragma unroll
        for (int nf = 0; nf < 4; ++nf) {
            float d    = acc[nf][reg];
            float hval = d * sc + sh;
            hval       = hval / (1.f + __expf(-hval));
            s_ += hval;
            m_ = fmaxf(m_, hval);
            int p      = p0 + nf * 16 + l15;
            __bf16 hb  = (__bf16)hval;
            hout[((size_t)b * COUT + o) * NP + p] = *(ushort*)&hb;
        }
#pragma unroll
        for (int d = 1; d < 16; d <<= 1) {
            s_ += __shfl_xor(s_, d, 64);
            m_ = fmaxf(m_, __shfl_xor(m_, d, 64));
        }
        if (l15 == 0) {
            atomicAdd(&sumh[b * COUT + o], s_);
            atomicMax(&mxenc[b * COUT + o], fenc(m_));
        }
    }
}

// ---------------------------------------------------------------------------
// Kernel 2: fused tail — ca MLP, spatial stats, 7x7 conv, weighted sum, LN.
// One block per image, 1024 threads. Block i -> image (i&7)*4 + i/8 so the
// tail block lands on the XCD that produced h[b] (k_main: XCD = b/4).
// ---------------------------------------------------------------------------
__global__ __launch_bounds__(1024) void k_tail(
    const ushort* __restrict__ h, const float* __restrict__ sumh,
    const unsigned* __restrict__ mxenc,
    const float* __restrict__ w1, const float* __restrict__ w2,
    const float* __restrict__ saw,
    const float* __restrict__ ln_g, const float* __restrict__ ln_b,
    float* __restrict__ out)
{
    const int i = blockIdx.x;
    const int b = (i & 7) * 4 + (i >> 3);
    const int t = threadIdx.x;
    const int wv = t >> 6, lane = t & 63;

    __shared__ float s0[NP];      // channel-mean plane  (12.5 KB)
    __shared__ float s1[NP];      // channel-max plane
    __shared__ float sg[NP];      // sigmoid(conv)
    __shared__ float cas[COUT];
    __shared__ float w[98];
    __shared__ float r1[16];
    __shared__ float yv[COUT];
    __shared__ float red[4];

    const ushort* hb = h + (size_t)b * COUT * NP;

    // ---- phase 0: channel attention (reuse s0/s1 as avg/max temporaries)
    if (t < 98) w[t] = saw[t];
    if (t < COUT) {
        s0[t] = sumh[b * COUT + t] * (1.f / (float)NP);
        s1[t] = fdec(mxenc[b * COUT + t]);
    }
    __syncthreads();
    if (t < 16) {
        int r = t & 7;
        const float* p = (t < 8) ? s0 : s1;
        float s = 0.f;
        for (int c = 0; c < COUT; ++c) s += w1[r * COUT + c] * p[c];
        r1[t] = fmaxf(s, 0.f);
    }
    __syncthreads();
    if (t < COUT) {
        float s = 0.f;
#pragma unroll
        for (int r = 0; r < 8; ++r) s += w2[t * 8 + r] * (r1[r] + r1[r + 8]);
        cas[t] = 1.f / (1.f + __expf(-s));
    }
    __syncthreads();

    // ---- phase 1: per-position channel sum/max of h*ca.
    // Pair pp1 = t (all), pp2 = t+1024 (t < 544). 1568 pairs total.
    {
        float a0 = 0.f, a1 = 0.f, m0 = -1e30f, m1 = -1e30f;
        float a2 = 0.f, a3 = 0.f, m2 = -1e30f, m3 = -1e30f;
        const bool two = (t + 1024) < (NP / 2);
        for (int c = 0; c < COUT; ++c) {
            float cv = cas[c];
            const ushort* hr = hb + (size_t)c * NP;
            unsigned u = *(const unsigned*)(hr + 2 * t);
            float v0 = bflo(u) * cv, v1 = bfhi(u) * cv;
            a0 += v0; a1 += v1;
            m0 = fmaxf(m0, v0); m1 = fmaxf(m1, v1);
            if (two) {
                unsigned q = *(const unsigned*)(hr + 2 * (t + 1024));
                float v2 = bflo(q) * cv, v3 = bfhi(q) * cv;
                a2 += v2; a3 += v3;
                m2 = fmaxf(m2, v2); m3 = fmaxf(m3, v3);
            }
        }
        s0[2 * t]     = a0 * (1.f / (float)COUT);
        s0[2 * t + 1] = a1 * (1.f / (float)COUT);
        s1[2 * t]     = m0;
        s1[2 * t + 1] = m1;
        if (two) {
            int p = 2 * (t + 1024);
            s0[p]     = a2 * (1.f / (float)COUT);
            s0[p + 1] = a3 * (1.f / (float)COUT);
            s1[p]     = m2;
            s1[p + 1] = m3;
        }
    }
    __syncthreads();

    // ---- phase 2: 7x7 conv (pad 3) + sigmoid -> sg
    for (int p = t; p < NP; p += 1024) {
        int py = p / WIMG, px = p % WIMG;
        float a = 0.f;
#pragma unroll
        for (int dy = 0; dy < 7; ++dy) {
            int yy = py + dy - 3;
            if (yy < 0 || yy >= WIMG) continue;
            int li = yy * WIMG;
            for (int dx = 0; dx < 7; ++dx) {
                int xx = px + dx - 3;
                if (xx < 0 || xx >= WIMG) continue;
                a += s0[li + xx] * w[dy * 7 + dx] + s1[li + xx] * w[49 + dy * 7 + dx];
            }
        }
        sg[p] = 1.f / (1.f + __expf(-a));
    }
    __syncthreads();

    // ---- phase 3: per-channel weighted sum; wave wv handles o = wv*8..+7
#pragma unroll
    for (int oo = 0; oo < 8; ++oo) {
        int o = wv * 8 + oo;
        const ushort* hr = hb + (size_t)o * NP;
        float s = 0.f;
#pragma unroll
        for (int j = 0; j < 12; ++j) {
            int q = j * 64 + lane;       // quad of positions, q < 768
            uint2 u = *(const uint2*)(hr + 4 * q);
            s += bflo(u.x) * sg[4 * q]     + bfhi(u.x) * sg[4 * q + 1]
               + bflo(u.y) * sg[4 * q + 2] + bfhi(u.y) * sg[4 * q + 3];
        }
        if (lane < 16) {
            int q = 768 + lane;          // 784 quads total
            uint2 u = *(const uint2*)(hr + 4 * q);
            s += bflo(u.x) * sg[4 * q]     + bfhi(u.x) * sg[4 * q + 1]
               + bflo(u.y) * sg[4 * q + 2] + bfhi(u.y) * sg[4 * q + 3];
        }
#pragma unroll
        for (int d = 1; d < 64; d <<= 1) s += __shfl_xor(s, d, 64);
        if (lane == 0)
            yv[o] = (sumh[b * COUT + o] + cas[o] * s) * (1.f / (float)NP);
    }
    __syncthreads();

    // ---- phase 4: LayerNorm over the 128 channels
    if (t < COUT) {
        float v = yv[t];
        float s = v;
#pragma unroll
        for (int d = 1; d < 64; d <<= 1) s += __shfl_xor(s, d, 64);
        if ((t & 63) == 0) red[t >> 6] = s;
    }
    __syncthreads();
    if (t < COUT) {
        float mu = (red[0] + red[1]) * (1.f / (float)COUT);
        float dv = yv[t] - mu;
        float q = dv * dv;
#pragma unroll
        for (int d = 1; d < 64; d <<= 1) q += __shfl_xor(q, d, 64);
        if ((t & 63) == 0) red[2 + (t >> 6)] = q;
    }
    __syncthreads();
    if (t < COUT) {
        float mu  = (red[0] + red[1]) * (1.f / (float)COUT);
        float var = (red[2] + red[3]) * (1.f / (float)COUT);
        float dv  = yv[t] - mu;
        out[b * COUT + t] = dv * rsqrtf(var + 1e-5f) * ln_g[t] + ln_b[t];
    }
}

// ---------------------------------------------------------------------------
extern "C" void kernel_launch(void* const* d_in, const int* in_sizes, int n_in,
                              void* d_out, int out_size, void* d_ws, size_t ws_size,
                              hipStream_t stream)
{
    const float* x     = (const float*)d_in[0];
    const float* wp    = (const float*)d_in[1];
    const float* bn_g  = (const float*)d_in[2];
    const float* bn_b  = (const float*)d_in[3];
    const float* bn_m  = (const float*)d_in[4];
    const float* bn_v  = (const float*)d_in[5];
    const float* ca_w1 = (const float*)d_in[6];
    const float* ca_w2 = (const float*)d_in[7];
    const float* sa_w  = (const float*)d_in[8];
    const float* ln_g  = (const float*)d_in[9];
    const float* ln_b  = (const float*)d_in[10];
    float* out = (float*)d_out;

    char* ws = (char*)d_ws;
    size_t off = 0;
    ushort*   hbuf  = (ushort*)(ws + off);   off += (size_t)NB * COUT * NP * 2;  // 25.7 MB
    float*    sumh  = (float*)(ws + off);    off += NB * COUT * 4;               // 16 KB
    unsigned* mxenc = (unsigned*)(ws + off); off += NB * COUT * 4;               // 16 KB
    ushort*   wb16  = (ushort*)(ws + off);   off += (size_t)COUT * CIN * 2;      // 128 KB

    k_wcvt<<<64, 256, 0, stream>>>(wp, wb16, (unsigned*)sumh);
    k_main<<<NB * 49, 512, 0, stream>>>(x, wb16, bn_g, bn_b, bn_m, bn_v, hbuf, sumh, mxenc);
    k_tail<<<NB, 1024, 0, stream>>>(hbuf, sumh, mxenc, ca_w1, ca_w2, sa_w, ln_g, ln_b, out);
}

// Round 7
// 86.595 us; speedup vs baseline: 1.5798x; 1.5798x over previous
//
#include <hip/hip_runtime.h>
#include <hip/hip_bf16.h>

typedef __bf16 bf16x8 __attribute__((ext_vector_type(8)));
typedef float f32x4 __attribute__((ext_vector_type(4)));

#define NB 32
#define CIN 512
#define COUT 128
#define NP 3136   // 56*56
#define WIMG 56

__device__ __forceinline__ unsigned fenc(float f) {
    unsigned u = __float_as_uint(f);
    return (u & 0x80000000u) ? ~u : (u | 0x80000000u);
}
__device__ __forceinline__ float fdec(unsigned e) {
    unsigned u = (e & 0x80000000u) ? (e ^ 0x80000000u) : ~e;
    return __uint_as_float(u);
}
__device__ __forceinline__ float bflo(unsigned u) { return __uint_as_float(u << 16); }
__device__ __forceinline__ float bfhi(unsigned u) { return __uint_as_float(u & 0xffff0000u); }

// Relaxed barrier: LDS-visibility only, no vmcnt drain (keep prefetch in flight).
__device__ __forceinline__ void lds_barrier() {
    asm volatile("s_waitcnt lgkmcnt(0)" ::: "memory");
    __builtin_amdgcn_s_barrier();
    __builtin_amdgcn_sched_barrier(0);
}

// ---------------------------------------------------------------------------
// Kernel 0: W f32 -> bf16, plus zero-init of sumh/mxenc.
// ---------------------------------------------------------------------------
__global__ __launch_bounds__(256) void k_wcvt(const float* __restrict__ wp,
                                              ushort* __restrict__ wb,
                                              unsigned* __restrict__ zero8k)
{
    int i = blockIdx.x * 256 + threadIdx.x;   // 16384 threads, 4 elems each
    if (i < 2 * NB * COUT) zero8k[i] = 0u;
    float4 f = *(const float4*)(wp + i * 4);
    ushort4 u;
    __bf16 b0 = (__bf16)f.x, b1 = (__bf16)f.y, b2 = (__bf16)f.z, b3 = (__bf16)f.w;
    u.x = *(ushort*)&b0; u.y = *(ushort*)&b1; u.z = *(ushort*)&b2; u.w = *(ushort*)&b3;
    *(ushort4*)(wb + i * 4) = u;
}

// ---------------------------------------------------------------------------
// Kernel 1: GEMM (W[128,512] @ X_b[512,3136]) + BN + SiLU, store h (bf16),
// accumulate per-(b,o) spatial sum and max. XCD-aware swizzle: XCD k owns
// images 4k..4k+3. Epilogue stages the h-tile in LDS and writes coalesced
// dwordx4 (128B-per-row chunks) instead of 32B scatter.
// ---------------------------------------------------------------------------
__global__ __launch_bounds__(512, 4) void k_main(
    const float* __restrict__ x, const ushort* __restrict__ wb,
    const float* __restrict__ bn_g, const float* __restrict__ bn_b,
    const float* __restrict__ bn_m, const float* __restrict__ bn_v,
    ushort* __restrict__ hout, float* __restrict__ sumh, unsigned* __restrict__ mxenc)
{
    __shared__ __align__(16) ushort Xs[2][64 * 64];  // 8KB each; reused as h-tile
    __shared__ float bnss[256];

    const int bid  = blockIdx.x;                    // 0..1567, 1568 % 8 == 0
    const int swz  = (bid & 7) * 196 + (bid >> 3);  // bijective XCD swizzle
    const int t    = threadIdx.x;
    const int b    = swz / 49;
    const int p0   = (swz % 49) * 64;
    const int lane = t & 63;
    const int l15  = lane & 15;
    const int lg   = lane >> 4;     // 0..3
    const int w    = t >> 6;        // wave 0..7

    if (t < COUT) {
        float sc = bn_g[t] * rsqrtf(bn_v[t] + 1e-5f);
        bnss[t]        = sc;
        bnss[t + COUT] = bn_b[t] - bn_m[t] * sc;
    }

    // ---- A-fragments (W) for the whole K dimension: 16 x bf16x8 = 64 VGPR
    const ushort* wrow = wb + (w * 16 + l15) * CIN + lg * 8;
    bf16x8 af[16];
#pragma unroll
    for (int ks = 0; ks < 16; ++ks)
        af[ks] = *(const bf16x8*)(wrow + ks * 32);

    // ---- staging geometry: thread t stages row p=t&63, k-octet kg=w
    const int pr = t & 63;
    const int kg = w;
    const float* xb = x + ((size_t)b * CIN) * NP + p0 + pr;
    const int wbyte = pr * 128 + ((kg * 16) ^ ((pr & 7) << 4));

    f32x4 acc[4];
#pragma unroll
    for (int nf = 0; nf < 4; ++nf) acc[nf] = (f32x4){0.f, 0.f, 0.f, 0.f};

    float ld[2][8];

    // prologue: issue tiles 0 and 1; write tile 0 into buf 0
#pragma unroll
    for (int j = 0; j < 8; ++j) ld[0][j] = xb[(kg * 8 + j) * NP];
#pragma unroll
    for (int j = 0; j < 8; ++j) ld[1][j] = xb[(64 + kg * 8 + j) * NP];
    {
        bf16x8 v8;
#pragma unroll
        for (int j = 0; j < 8; ++j) v8[j] = (__bf16)ld[0][j];
        *(bf16x8*)((char*)Xs[0] + wbyte) = v8;
    }

#pragma unroll
    for (int kc = 0; kc < 8; ++kc) {
        lds_barrier();
        // issue tile kc+2 into the reg set freed by tile kc (distance-2 prefetch)
        if (kc < 6) {
#pragma unroll
            for (int j = 0; j < 8; ++j)
                ld[kc & 1][j] = xb[((kc + 2) * 64 + kg * 8 + j) * NP];
        }
        // compute current tile from Xs[kc&1]
#pragma unroll
        for (int ks = 0; ks < 2; ++ks) {
#pragma unroll
            for (int nf = 0; nf < 4; ++nf) {
                int row  = nf * 16 + l15;
                int byte = row * 128 + ((ks * 64 + lg * 16) ^ ((row & 7) << 4));
                bf16x8 bfr = *(const bf16x8*)((const char*)Xs[kc & 1] + byte);
                acc[nf] = __builtin_amdgcn_mfma_f32_16x16x32_bf16(
                    af[kc * 2 + ks], bfr, acc[nf], 0, 0, 0);
            }
        }
        // write-late: cvt + ds_write tile kc+1 (issued one iteration ago)
        if (kc < 7) {
            bf16x8 v8;
#pragma unroll
            for (int j = 0; j < 8; ++j) v8[j] = (__bf16)ld[(kc + 1) & 1][j];
            *(bf16x8*)((char*)Xs[(kc + 1) & 1] + wbyte) = v8;
        }
    }

    // ---- epilogue: BN + SiLU, per-(b,o) sum/max; h staged in LDS then
    // written coalesced (dwordx4, 128B per row-chunk).
    __syncthreads();                 // all Xs reads done before reuse
    ushort* Hs = (ushort*)Xs;        // [128 o][64 p] = 16KB
#pragma unroll
    for (int reg = 0; reg < 4; ++reg) {
        int o = w * 16 + lg * 4 + reg;
        float sc = bnss[o], sh = bnss[o + COUT];
        float s_ = 0.f, m_ = -1e30f;
#pragma unroll
        for (int nf = 0; nf < 4; ++nf) {
            float d    = acc[nf][reg];
            float hval = d * sc + sh;
            hval       = hval / (1.f + __expf(-hval));
            s_ += hval;
            m_ = fmaxf(m_, hval);
            __bf16 hb  = (__bf16)hval;
            Hs[o * 64 + nf * 16 + l15] = *(ushort*)&hb;
        }
#pragma unroll
        for (int d = 1; d < 16; d <<= 1) {
            s_ += __shfl_xor(s_, d, 64);
            m_ = fmaxf(m_, __shfl_xor(m_, d, 64));
        }
        if (l15 == 0) {
            atomicAdd(&sumh[b * COUT + o], s_);
            atomicMax(&mxenc[b * COUT + o], fenc(m_));
        }
    }
    __syncthreads();
#pragma unroll
    for (int r = 0; r < 2; ++r) {
        int idx  = r * 512 + t;
        int orow = idx >> 3, c = idx & 7;
        uint4 v = *(const uint4*)&Hs[orow * 64 + c * 8];
        *(uint4*)&hout[((size_t)b * COUT + orow) * NP + p0 + c * 8] = v;
    }
}

// ---------------------------------------------------------------------------
// Kernel 2: spatial stats of (h * ca). Computes the channel-attention MLP
// inline (removes the k_ca launch); block x==0 publishes ca for k_wsum.
// sbuf[z][b][{sum,max}][p], channel-split 4 ways.
// ---------------------------------------------------------------------------
__global__ __launch_bounds__(256) void k_sstat(const ushort* __restrict__ h,
                                               const float* __restrict__ sumh,
                                               const unsigned* __restrict__ mxenc,
                                               const float* __restrict__ w1,
                                               const float* __restrict__ w2,
                                               float* __restrict__ ca,
                                               float* __restrict__ sbuf)
{
    int b = blockIdx.y, z = blockIdx.z;
    int t = threadIdx.x;
    __shared__ float avg[128], mx[128], r1[16], cas[32];
    if (t < 128) {
        avg[t] = sumh[b * COUT + t] * (1.f / (float)NP);
        mx[t]  = fdec(mxenc[b * COUT + t]);
    }
    __syncthreads();
    if (t < 16) {
        int r = t & 7;
        const float* p = (t < 8) ? avg : mx;
        float s = 0.f;
        for (int c = 0; c < 128; ++c) s += w1[r * 128 + c] * p[c];
        r1[t] = fmaxf(s, 0.f);
    }
    __syncthreads();
    if (t < 32) {
        int o = z * 32 + t;
        float s = 0.f;
#pragma unroll
        for (int r = 0; r < 8; ++r) s += w2[o * 8 + r] * (r1[r] + r1[r + 8]);
        float cv = 1.f / (1.f + __expf(-s));
        cas[t] = cv;
        if (blockIdx.x == 0) ca[b * COUT + o] = cv;
    }
    __syncthreads();

    int pp = blockIdx.x * 256 + t;  // pair index
    if (pp >= NP / 2) return;
    int p = pp * 2;
    const ushort* hb = h + ((size_t)b * COUT + z * 32) * NP + p;
    float s0 = 0.f, s1 = 0.f, m0 = -1e30f, m1 = -1e30f;
#pragma unroll 4
    for (int c = 0; c < 32; ++c) {
        unsigned u = *(const unsigned*)(hb + (size_t)c * NP);
        float cv = cas[c];
        float v0 = bflo(u) * cv;
        float v1 = bfhi(u) * cv;
        s0 += v0; s1 += v1;
        m0 = fmaxf(m0, v0); m1 = fmaxf(m1, v1);
    }
    float* sb = sbuf + ((size_t)(z * NB + b) * 2) * NP;
    sb[p] = s0; sb[p + 1] = s1;
    sb[NP + p] = m0; sb[NP + p + 1] = m1;
}

// ---------------------------------------------------------------------------
// Kernel 3: combine quarters, 7x7 conv (pad 3) + sigmoid -> sigsa[32,3136]
// Row-band parallel: grid (8 bands x NB), each band = 7 rows + 3-row halo.
// ---------------------------------------------------------------------------
__global__ __launch_bounds__(256) void k_conv(const float* __restrict__ sbuf,
                                              const float* __restrict__ saw,
                                              float* __restrict__ sigsa)
{
    int band = blockIdx.x, b = blockIdx.y;
    int y0 = band * 7;
    int t = threadIdx.x;
    __shared__ float s[2][13 * WIMG];
    __shared__ float w[98];
    if (t < 98) w[t] = saw[t];
    for (int i = t; i < 13 * WIMG; i += 256) {
        int yy = y0 - 3 + i / WIMG;
        float vs = 0.f, vm = 0.f;
        if (yy >= 0 && yy < WIMG) {
            int p = yy * WIMG + (i % WIMG);
            float ssum = 0.f, smax = -1e30f;
#pragma unroll
            for (int z = 0; z < 4; ++z) {
                const float* sb = sbuf + ((size_t)(z * NB + b) * 2) * NP;
                ssum += sb[p];
                smax = fmaxf(smax, sb[NP + p]);
            }
            vs = ssum * (1.f / (float)COUT);
            vm = smax;
        }
        s[0][i] = vs;
        s[1][i] = vm;
    }
    __syncthreads();
    for (int i = t; i < 7 * WIMG; i += 256) {
        int ly = i / WIMG, px = i % WIMG;
        float a = 0.f;
#pragma unroll
        for (int ch = 0; ch < 2; ++ch) {
#pragma unroll
            for (int dy = 0; dy < 7; ++dy) {
                int li = (ly + dy) * WIMG;
                for (int dx = 0; dx < 7; ++dx) {
                    int xx = px + dx - 3;
                    if (xx < 0 || xx >= WIMG) continue;
                    a += s[ch][li + xx] * w[ch * 49 + dy * 7 + dx];
                }
            }
        }
        sigsa[b * NP + (y0 + ly) * WIMG + px] = 1.f / (1.f + __expf(-a));
    }
}

// ---------------------------------------------------------------------------
// Kernel 4: t = sum_p h * sigsa ; y = (sum_h + ca*t)/P.  One block per (b,o).
// ---------------------------------------------------------------------------
__global__ __launch_bounds__(256) void k_wsum(const ushort* __restrict__ h,
                                              const float* __restrict__ sigsa,
                                              const float* __restrict__ sumh,
                                              const float* __restrict__ ca,
                                              float* __restrict__ y)
{
    int bo = blockIdx.x;          // b*128+o
    int b = bo >> 7;
    int t = threadIdx.x;
    const ushort* hr = h + (size_t)bo * NP;
    const float* sg  = sigsa + (size_t)b * NP;
    float s = 0.f;
#pragma unroll
    for (int i = 0; i < 3; ++i) {
        int q = (i * 256 + t) * 4;
        uint2 u = *(const uint2*)(hr + q);
        float4 g = *(const float4*)(sg + q);
        s += bflo(u.x) * g.x + bfhi(u.x) * g.y + bflo(u.y) * g.z + bfhi(u.y) * g.w;
    }
    if (t < 16) {
        int q = (768 + t) * 4;
        uint2 u = *(const uint2*)(hr + q);
        float4 g = *(const float4*)(sg + q);
        s += bflo(u.x) * g.x + bfhi(u.x) * g.y + bflo(u.y) * g.z + bfhi(u.y) * g.w;
    }
#pragma unroll
    for (int d = 1; d < 64; d <<= 1) s += __shfl_xor(s, d, 64);
    __shared__ float part[4];
    if ((t & 63) == 0) part[t >> 6] = s;
    __syncthreads();
    if (t == 0) {
        float tt = part[0] + part[1] + part[2] + part[3];
        y[bo] = (sumh[bo] + ca[bo] * tt) * (1.f / (float)NP);
    }
}

// ---------------------------------------------------------------------------
// Kernel 5: LayerNorm over channels -> out[32,128]
// ---------------------------------------------------------------------------
__global__ void k_ln(const float* __restrict__ y, const float* __restrict__ g,
                     const float* __restrict__ bta, float* __restrict__ out)
{
    int b = blockIdx.x, t = threadIdx.x;  // 128 threads
    __shared__ float pr[2], pr2[2];
    float v = y[b * COUT + t];
    float s = v;
#pragma unroll
    for (int d = 1; d < 64; d <<= 1) s += __shfl_xor(s, d, 64);
    if ((t & 63) == 0) pr[t >> 6] = s;
    __syncthreads();
    float mu = (pr[0] + pr[1]) * (1.f / (float)COUT);
    float dv = v - mu;
    float q = dv * dv;
#pragma unroll
    for (int d = 1; d < 64; d <<= 1) q += __shfl_xor(q, d, 64);
    if ((t & 63) == 0) pr2[t >> 6] = q;
    __syncthreads();
    float var = (pr2[0] + pr2[1]) * (1.f / (float)COUT);
    out[b * COUT + t] = dv * rsqrtf(var + 1e-5f) * g[t] + bta[t];
}

// ---------------------------------------------------------------------------
extern "C" void kernel_launch(void* const* d_in, const int* in_sizes, int n_in,
                              void* d_out, int out_size, void* d_ws, size_t ws_size,
                              hipStream_t stream)
{
    const float* x     = (const float*)d_in[0];
    const float* wp    = (const float*)d_in[1];
    const float* bn_g  = (const float*)d_in[2];
    const float* bn_b  = (const float*)d_in[3];
    const float* bn_m  = (const float*)d_in[4];
    const float* bn_v  = (const float*)d_in[5];
    const float* ca_w1 = (const float*)d_in[6];
    const float* ca_w2 = (const float*)d_in[7];
    const float* sa_w  = (const float*)d_in[8];
    const float* ln_g  = (const float*)d_in[9];
    const float* ln_b  = (const float*)d_in[10];
    float* out = (float*)d_out;

    char* ws = (char*)d_ws;
    size_t off = 0;
    ushort*   hbuf  = (ushort*)(ws + off);   off += (size_t)NB * COUT * NP * 2;  // 25.7 MB
    float*    sumh  = (float*)(ws + off);    off += NB * COUT * 4;               // 16 KB
    unsigned* mxenc = (unsigned*)(ws + off); off += NB * COUT * 4;               // 16 KB
    float*    ca    = (float*)(ws + off);    off += NB * COUT * 4;               // 16 KB
    float*    sbuf  = (float*)(ws + off);    off += (size_t)4 * NB * 2 * NP * 4; // 3.2 MB
    float*    sigsa = (float*)(ws + off);    off += (size_t)NB * NP * 4;         // 0.4 MB
    float*    ybuf  = (float*)(ws + off);    off += NB * COUT * 4;
    ushort*   wb16  = (ushort*)(ws + off);   off += (size_t)COUT * CIN * 2;      // 128 KB

    k_wcvt<<<64, 256, 0, stream>>>(wp, wb16, (unsigned*)sumh);
    k_main<<<NB * 49, 512, 0, stream>>>(x, wb16, bn_g, bn_b, bn_m, bn_v, hbuf, sumh, mxenc);
    k_sstat<<<dim3(7, NB, 4), 256, 0, stream>>>(hbuf, sumh, mxenc, ca_w1, ca_w2, ca, sbuf);
    k_conv<<<dim3(8, NB), 256, 0, stream>>>(sbuf, sa_w, sigsa);
    k_wsum<<<NB * COUT, 256, 0, stream>>>(hbuf, sigsa, sumh, ca, ybuf);
    k_ln<<<NB, 128, 0, stream>>>(ybuf, ln_g, ln_b, out);
}

// Round 8
// 85.772 us; speedup vs baseline: 1.5950x; 1.0096x over previous
//
#include <hip/hip_runtime.h>
#include <hip/hip_bf16.h>

typedef __bf16 bf16x8 __attribute__((ext_vector_type(8)));
typedef float f32x4 __attribute__((ext_vector_type(4)));

#define NB 32
#define CIN 512
#define COUT 128
#define NP 3136   // 56*56
#define WIMG 56

__device__ __forceinline__ unsigned fenc(float f) {
    unsigned u = __float_as_uint(f);
    return (u & 0x80000000u) ? ~u : (u | 0x80000000u);
}
__device__ __forceinline__ float fdec(unsigned e) {
    unsigned u = (e & 0x80000000u) ? (e ^ 0x80000000u) : ~e;
    return __uint_as_float(u);
}
__device__ __forceinline__ float bflo(unsigned u) { return __uint_as_float(u << 16); }
__device__ __forceinline__ float bfhi(unsigned u) { return __uint_as_float(u & 0xffff0000u); }

// Relaxed barrier: LDS-visibility only, no vmcnt drain (keep prefetch in flight).
__device__ __forceinline__ void lds_barrier() {
    asm volatile("s_waitcnt lgkmcnt(0)" ::: "memory");
    __builtin_amdgcn_s_barrier();
    __builtin_amdgcn_sched_barrier(0);
}

// ---------------------------------------------------------------------------
// Kernel 0: W f32 -> bf16, plus zero-init of sumh/mxenc.
// ---------------------------------------------------------------------------
__global__ __launch_bounds__(256) void k_wcvt(const float* __restrict__ wp,
                                              ushort* __restrict__ wb,
                                              unsigned* __restrict__ zero8k)
{
    int i = blockIdx.x * 256 + threadIdx.x;   // 16384 threads, 4 elems each
    if (i < 2 * NB * COUT) zero8k[i] = 0u;
    float4 f = *(const float4*)(wp + i * 4);
    ushort4 u;
    __bf16 b0 = (__bf16)f.x, b1 = (__bf16)f.y, b2 = (__bf16)f.z, b3 = (__bf16)f.w;
    u.x = *(ushort*)&b0; u.y = *(ushort*)&b1; u.z = *(ushort*)&b2; u.w = *(ushort*)&b3;
    *(ushort4*)(wb + i * 4) = u;
}

// ---------------------------------------------------------------------------
// Kernel 1: GEMM (W[128,512] @ X_b[512,3136]) + BN + SiLU, store h (bf16),
// accumulate per-(b,o) spatial sum and max. XCD-aware swizzle. Distance-3
// register prefetch (3 slots, ~2.3-iteration / ~600cy in-flight window).
// Epilogue stages h-tile in LDS, writes coalesced dwordx4.
// ---------------------------------------------------------------------------
__global__ __launch_bounds__(512, 4) void k_main(
    const float* __restrict__ x, const ushort* __restrict__ wb,
    const float* __restrict__ bn_g, const float* __restrict__ bn_b,
    const float* __restrict__ bn_m, const float* __restrict__ bn_v,
    ushort* __restrict__ hout, float* __restrict__ sumh, unsigned* __restrict__ mxenc)
{
    __shared__ __align__(16) ushort Xs[2][64 * 64];  // 8KB each; reused as h-tile
    __shared__ float bnss[256];

    const int bid  = blockIdx.x;                    // 0..1567, 1568 % 8 == 0
    const int swz  = (bid & 7) * 196 + (bid >> 3);  // bijective XCD swizzle
    const int t    = threadIdx.x;
    const int b    = swz / 49;
    const int p0   = (swz % 49) * 64;
    const int lane = t & 63;
    const int l15  = lane & 15;
    const int lg   = lane >> 4;     // 0..3
    const int w    = t >> 6;        // wave 0..7

    if (t < COUT) {
        float sc = bn_g[t] * rsqrtf(bn_v[t] + 1e-5f);
        bnss[t]        = sc;
        bnss[t + COUT] = bn_b[t] - bn_m[t] * sc;
    }

    // ---- A-fragments (W) for the whole K dimension: 16 x bf16x8 = 64 VGPR
    const ushort* wrow = wb + (w * 16 + l15) * CIN + lg * 8;
    bf16x8 af[16];
#pragma unroll
    for (int ks = 0; ks < 16; ++ks)
        af[ks] = *(const bf16x8*)(wrow + ks * 32);

    // ---- staging geometry: thread t stages row p=t&63, k-octet kg=w
    const int pr = t & 63;
    const int kg = w;
    const float* xb = x + ((size_t)b * CIN) * NP + p0 + pr;
    const int wbyte = pr * 128 + ((kg * 16) ^ ((pr & 7) << 4));

    f32x4 acc[4];
#pragma unroll
    for (int nf = 0; nf < 4; ++nf) acc[nf] = (f32x4){0.f, 0.f, 0.f, 0.f};

    float ld[3][8];   // distance-3 prefetch slots; tile j lives in slot j%3

    // prologue: issue tiles 0,1,2; write tile 0 into buf 0
#pragma unroll
    for (int s = 0; s < 3; ++s)
#pragma unroll
        for (int j = 0; j < 8; ++j) ld[s][j] = xb[(s * 64 + kg * 8 + j) * NP];
    {
        bf16x8 v8;
#pragma unroll
        for (int j = 0; j < 8; ++j) v8[j] = (__bf16)ld[0][j];
        *(bf16x8*)((char*)Xs[0] + wbyte) = v8;
    }

#pragma unroll
    for (int kc = 0; kc < 8; ++kc) {
        lds_barrier();
        // issue tile kc+3 into slot kc%3 (freed by tile kc at iter kc-1)
        if (kc < 5) {
#pragma unroll
            for (int j = 0; j < 8; ++j)
                ld[kc % 3][j] = xb[((kc + 3) * 64 + kg * 8 + j) * NP];
        }
        // compute current tile from Xs[kc&1]
#pragma unroll
        for (int ks = 0; ks < 2; ++ks) {
#pragma unroll
            for (int nf = 0; nf < 4; ++nf) {
                int row  = nf * 16 + l15;
                int byte = row * 128 + ((ks * 64 + lg * 16) ^ ((row & 7) << 4));
                bf16x8 bfr = *(const bf16x8*)((const char*)Xs[kc & 1] + byte);
                acc[nf] = __builtin_amdgcn_mfma_f32_16x16x32_bf16(
                    af[kc * 2 + ks], bfr, acc[nf], 0, 0, 0);
            }
        }
        // write-late: cvt + ds_write tile kc+1 (issued at iter kc-2)
        if (kc < 7) {
            bf16x8 v8;
#pragma unroll
            for (int j = 0; j < 8; ++j) v8[j] = (__bf16)ld[(kc + 1) % 3][j];
            *(bf16x8*)((char*)Xs[(kc + 1) & 1] + wbyte) = v8;
        }
    }

    // ---- epilogue: BN + SiLU, per-(b,o) sum/max; h staged in LDS then
    // written coalesced (dwordx4, 128B per row-chunk).
    __syncthreads();                 // all Xs reads done before reuse
    ushort* Hs = (ushort*)Xs;        // [128 o][64 p] = 16KB
#pragma unroll
    for (int reg = 0; reg < 4; ++reg) {
        int o = w * 16 + lg * 4 + reg;
        float sc = bnss[o], sh = bnss[o + COUT];
        float s_ = 0.f, m_ = -1e30f;
#pragma unroll
        for (int nf = 0; nf < 4; ++nf) {
            float d    = acc[nf][reg];
            float hval = d * sc + sh;
            hval       = hval / (1.f + __expf(-hval));
            s_ += hval;
            m_ = fmaxf(m_, hval);
            __bf16 hb  = (__bf16)hval;
            Hs[o * 64 + nf * 16 + l15] = *(ushort*)&hb;
        }
#pragma unroll
        for (int d = 1; d < 16; d <<= 1) {
            s_ += __shfl_xor(s_, d, 64);
            m_ = fmaxf(m_, __shfl_xor(m_, d, 64));
        }
        if (l15 == 0) {
            atomicAdd(&sumh[b * COUT + o], s_);
            atomicMax(&mxenc[b * COUT + o], fenc(m_));
        }
    }
    __syncthreads();
#pragma unroll
    for (int r = 0; r < 2; ++r) {
        int idx  = r * 512 + t;
        int orow = idx >> 3, c = idx & 7;
        uint4 v = *(const uint4*)&Hs[orow * 64 + c * 8];
        *(uint4*)&hout[((size_t)b * COUT + orow) * NP + p0 + c * 8] = v;
    }
}

// ---------------------------------------------------------------------------
// Kernel 2: spatial stats of (h * ca). Computes the channel-attention MLP
// inline; block x==0 publishes ca for k_wsum. sbuf[z][b][{sum,max}][p].
// ---------------------------------------------------------------------------
__global__ __launch_bounds__(256) void k_sstat(const ushort* __restrict__ h,
                                               const float* __restrict__ sumh,
                                               const unsigned* __restrict__ mxenc,
                                               const float* __restrict__ w1,
                                               const float* __restrict__ w2,
                                               float* __restrict__ ca,
                                               float* __restrict__ sbuf)
{
    int b = blockIdx.y, z = blockIdx.z;
    int t = threadIdx.x;
    __shared__ float avg[128], mx[128], r1[16], cas[32];
    if (t < 128) {
        avg[t] = sumh[b * COUT + t] * (1.f / (float)NP);
        mx[t]  = fdec(mxenc[b * COUT + t]);
    }
    __syncthreads();
    if (t < 16) {
        int r = t & 7;
        const float* p = (t < 8) ? avg : mx;
        float s = 0.f;
        for (int c = 0; c < 128; ++c) s += w1[r * 128 + c] * p[c];
        r1[t] = fmaxf(s, 0.f);
    }
    __syncthreads();
    if (t < 32) {
        int o = z * 32 + t;
        float s = 0.f;
#pragma unroll
        for (int r = 0; r < 8; ++r) s += w2[o * 8 + r] * (r1[r] + r1[r + 8]);
        float cv = 1.f / (1.f + __expf(-s));
        cas[t] = cv;
        if (blockIdx.x == 0) ca[b * COUT + o] = cv;
    }
    __syncthreads();

    int pp = blockIdx.x * 256 + t;  // pair index
    if (pp >= NP / 2) return;
    int p = pp * 2;
    const ushort* hb = h + ((size_t)b * COUT + z * 32) * NP + p;
    float s0 = 0.f, s1 = 0.f, m0 = -1e30f, m1 = -1e30f;
#pragma unroll 4
    for (int c = 0; c < 32; ++c) {
        unsigned u = *(const unsigned*)(hb + (size_t)c * NP);
        float cv = cas[c];
        float v0 = bflo(u) * cv;
        float v1 = bfhi(u) * cv;
        s0 += v0; s1 += v1;
        m0 = fmaxf(m0, v0); m1 = fmaxf(m1, v1);
    }
    float* sb = sbuf + ((size_t)(z * NB + b) * 2) * NP;
    sb[p] = s0; sb[p + 1] = s1;
    sb[NP + p] = m0; sb[NP + p + 1] = m1;
}

// ---------------------------------------------------------------------------
// Kernel 3: combine quarters, 7x7 conv (pad 3) + sigmoid -> sigsa[32,3136]
// Row-band parallel: grid (8 bands x NB), each band = 7 rows + 3-row halo.
// ---------------------------------------------------------------------------
__global__ __launch_bounds__(256) void k_conv(const float* __restrict__ sbuf,
                                              const float* __restrict__ saw,
                                              float* __restrict__ sigsa)
{
    int band = blockIdx.x, b = blockIdx.y;
    int y0 = band * 7;
    int t = threadIdx.x;
    __shared__ float s[2][13 * WIMG];
    __shared__ float w[98];
    if (t < 98) w[t] = saw[t];
    for (int i = t; i < 13 * WIMG; i += 256) {
        int yy = y0 - 3 + i / WIMG;
        float vs = 0.f, vm = 0.f;
        if (yy >= 0 && yy < WIMG) {
            int p = yy * WIMG + (i % WIMG);
            float ssum = 0.f, smax = -1e30f;
#pragma unroll
            for (int z = 0; z < 4; ++z) {
                const float* sb = sbuf + ((size_t)(z * NB + b) * 2) * NP;
                ssum += sb[p];
                smax = fmaxf(smax, sb[NP + p]);
            }
            vs = ssum * (1.f / (float)COUT);
            vm = smax;
        }
        s[0][i] = vs;
        s[1][i] = vm;
    }
    __syncthreads();
    for (int i = t; i < 7 * WIMG; i += 256) {
        int ly = i / WIMG, px = i % WIMG;
        float a = 0.f;
#pragma unroll
        for (int ch = 0; ch < 2; ++ch) {
#pragma unroll
            for (int dy = 0; dy < 7; ++dy) {
                int li = (ly + dy) * WIMG;
                for (int dx = 0; dx < 7; ++dx) {
                    int xx = px + dx - 3;
                    if (xx < 0 || xx >= WIMG) continue;
                    a += s[ch][li + xx] * w[ch * 49 + dy * 7 + dx];
                }
            }
        }
        sigsa[b * NP + (y0 + ly) * WIMG + px] = 1.f / (1.f + __expf(-a));
    }
}

// ---------------------------------------------------------------------------
// Kernel 4: t = sum_p h * sigsa ; y = (sum_h + ca*t)/P.  One block per (b,o).
// ---------------------------------------------------------------------------
__global__ __launch_bounds__(256) void k_wsum(const ushort* __restrict__ h,
                                              const float* __restrict__ sigsa,
                                              const float* __restrict__ sumh,
                                              const float* __restrict__ ca,
                                              float* __restrict__ y)
{
    int bo = blockIdx.x;          // b*128+o
    int b = bo >> 7;
    int t = threadIdx.x;
    const ushort* hr = h + (size_t)bo * NP;
    const float* sg  = sigsa + (size_t)b * NP;
    float s = 0.f;
#pragma unroll
    for (int i = 0; i < 3; ++i) {
        int q = (i * 256 + t) * 4;
        uint2 u = *(const uint2*)(hr + q);
        float4 g = *(const float4*)(sg + q);
        s += bflo(u.x) * g.x + bfhi(u.x) * g.y + bflo(u.y) * g.z + bfhi(u.y) * g.w;
    }
    if (t < 16) {
        int q = (768 + t) * 4;
        uint2 u = *(const uint2*)(hr + q);
        float4 g = *(const float4*)(sg + q);
        s += bflo(u.x) * g.x + bfhi(u.x) * g.y + bflo(u.y) * g.z + bfhi(u.y) * g.w;
    }
#pragma unroll
    for (int d = 1; d < 64; d <<= 1) s += __shfl_xor(s, d, 64);
    __shared__ float part[4];
    if ((t & 63) == 0) part[t >> 6] = s;
    __syncthreads();
    if (t == 0) {
        float tt = part[0] + part[1] + part[2] + part[3];
        y[bo] = (sumh[bo] + ca[bo] * tt) * (1.f / (float)NP);
    }
}

// ---------------------------------------------------------------------------
// Kernel 5: LayerNorm over channels -> out[32,128]
// ---------------------------------------------------------------------------
__global__ void k_ln(const float* __restrict__ y, const float* __restrict__ g,
                     const float* __restrict__ bta, float* __restrict__ out)
{
    int b = blockIdx.x, t = threadIdx.x;  // 128 threads
    __shared__ float pr[2], pr2[2];
    float v = y[b * COUT + t];
    float s = v;
#pragma unroll
    for (int d = 1; d < 64; d <<= 1) s += __shfl_xor(s, d, 64);
    if ((t & 63) == 0) pr[t >> 6] = s;
    __syncthreads();
    float mu = (pr[0] + pr[1]) * (1.f / (float)COUT);
    float dv = v - mu;
    float q = dv * dv;
#pragma unroll
    for (int d = 1; d < 64; d <<= 1) q += __shfl_xor(q, d, 64);
    if ((t & 63) == 0) pr2[t >> 6] = q;
    __syncthreads();
    float var = (pr2[0] + pr2[1]) * (1.f / (float)COUT);
    out[b * COUT + t] = dv * rsqrtf(var + 1e-5f) * g[t] + bta[t];
}

// ---------------------------------------------------------------------------
extern "C" void kernel_launch(void* const* d_in, const int* in_sizes, int n_in,
                              void* d_out, int out_size, void* d_ws, size_t ws_size,
                              hipStream_t stream)
{
    const float* x     = (const float*)d_in[0];
    const float* wp    = (const float*)d_in[1];
    const float* bn_g  = (const float*)d_in[2];
    const float* bn_b  = (const float*)d_in[3];
    const float* bn_m  = (const float*)d_in[4];
    const float* bn_v  = (const float*)d_in[5];
    const float* ca_w1 = (const float*)d_in[6];
    const float* ca_w2 = (const float*)d_in[7];
    const float* sa_w  = (const float*)d_in[8];
    const float* ln_g  = (const float*)d_in[9];
    const float* ln_b  = (const float*)d_in[10];
    float* out = (float*)d_out;

    char* ws = (char*)d_ws;
    size_t off = 0;
    ushort*   hbuf  = (ushort*)(ws + off);   off += (size_t)NB * COUT * NP * 2;  // 25.7 MB
    float*    sumh  = (float*)(ws + off);    off += NB * COUT * 4;               // 16 KB
    unsigned* mxenc = (unsigned*)(ws + off); off += NB * COUT * 4;               // 16 KB
    float*    ca    = (float*)(ws + off);    off += NB * COUT * 4;               // 16 KB
    float*    sbuf  = (float*)(ws + off);    off += (size_t)4 * NB * 2 * NP * 4; // 3.2 MB
    float*    sigsa = (float*)(ws + off);    off += (size_t)NB * NP * 4;         // 0.4 MB
    float*    ybuf  = (float*)(ws + off);    off += NB * COUT * 4;
    ushort*   wb16  = (ushort*)(ws + off);   off += (size_t)COUT * CIN * 2;      // 128 KB

    k_wcvt<<<64, 256, 0, stream>>>(wp, wb16, (unsigned*)sumh);
    k_main<<<NB * 49, 512, 0, stream>>>(x, wb16, bn_g, bn_b, bn_m, bn_v, hbuf, sumh, mxenc);
    k_sstat<<<dim3(7, NB, 4), 256, 0, stream>>>(hbuf, sumh, mxenc, ca_w1, ca_w2, ca, sbuf);
    k_conv<<<dim3(8, NB), 256, 0, stream>>>(sbuf, sa_w, sigsa);
    k_wsum<<<NB * COUT, 256, 0, stream>>>(hbuf, sigsa, sumh, ca, ybuf);
    k_ln<<<NB, 128, 0, stream>>>(ybuf, ln_g, ln_b, out);
}

// Round 9
// 83.992 us; speedup vs baseline: 1.6288x; 1.0212x over previous
//
#include <hip/hip_runtime.h>
#include <hip/hip_bf16.h>

typedef __bf16 bf16x8 __attribute__((ext_vector_type(8)));
typedef float f32x4 __attribute__((ext_vector_type(4)));

#define NB 32
#define CIN 512
#define COUT 128
#define NP 3136   // 56*56
#define WIMG 56

__device__ __forceinline__ unsigned fenc(float f) {
    unsigned u = __float_as_uint(f);
    return (u & 0x80000000u) ? ~u : (u | 0x80000000u);
}
__device__ __forceinline__ float fdec(unsigned e) {
    unsigned u = (e & 0x80000000u) ? (e ^ 0x80000000u) : ~e;
    return __uint_as_float(u);
}
__device__ __forceinline__ float bflo(unsigned u) { return __uint_as_float(u << 16); }
__device__ __forceinline__ float bfhi(unsigned u) { return __uint_as_float(u & 0xffff0000u); }

// Relaxed barrier: LDS-visibility only, no vmcnt drain (keep prefetch in flight).
__device__ __forceinline__ void lds_barrier() {
    asm volatile("s_waitcnt lgkmcnt(0)" ::: "memory");
    __builtin_amdgcn_s_barrier();
    __builtin_amdgcn_sched_barrier(0);
}

// ---------------------------------------------------------------------------
// Kernel 0: W f32 -> bf16, plus zero-init of sumh/mxenc.
// ---------------------------------------------------------------------------
__global__ __launch_bounds__(256) void k_wcvt(const float* __restrict__ wp,
                                              ushort* __restrict__ wb,
                                              unsigned* __restrict__ zero8k)
{
    int i = blockIdx.x * 256 + threadIdx.x;   // 16384 threads, 4 elems each
    if (i < 2 * NB * COUT) zero8k[i] = 0u;
    float4 f = *(const float4*)(wp + i * 4);
    ushort4 u;
    __bf16 b0 = (__bf16)f.x, b1 = (__bf16)f.y, b2 = (__bf16)f.z, b3 = (__bf16)f.w;
    u.x = *(ushort*)&b0; u.y = *(ushort*)&b1; u.z = *(ushort*)&b2; u.w = *(ushort*)&b3;
    *(ushort4*)(wb + i * 4) = u;
}

// ---------------------------------------------------------------------------
// Kernel 1: GEMM + BN + SiLU + h store + per-(b,o) sum/max.
// BM=128, BN=128 (strips 0..23; strip 24 is 64-wide). 512 threads, 8 waves
// in 4M x 2N. W staged per-kc in LDS (dbuf, dist-1 prefetch from L2-hot wb16);
// X tile [128p][64k] bf16 dbuf, dist-2 prefetch. 512B-contiguous x reads per
// channel-row per block (DRAM page locality — the R9 lever).
// ---------------------------------------------------------------------------
__global__ __launch_bounds__(512, 4) void k_main(
    const float* __restrict__ x, const ushort* __restrict__ wb,
    const float* __restrict__ bn_g, const float* __restrict__ bn_b,
    const float* __restrict__ bn_m, const float* __restrict__ bn_v,
    ushort* __restrict__ hout, float* __restrict__ sumh, unsigned* __restrict__ mxenc)
{
    __shared__ __align__(16) ushort Xs[2][128 * 64];  // 16KB each
    __shared__ __align__(16) ushort Ws[2][128 * 64];  // 16KB each
    __shared__ float bnss[256];

    const int bid   = blockIdx.x;                    // 0..799, 800 % 8 == 0
    const int swz   = (bid & 7) * 100 + (bid >> 3);  // 4 images per XCD
    const int b     = swz / 25;
    const int strip = swz % 25;
    const int p0    = strip * 128;
    const bool full = (strip < 24);                  // strip 24: 64 wide
    const int t    = threadIdx.x;
    const int lane = t & 63;
    const int l15  = lane & 15;
    const int lg   = lane >> 4;     // 0..3
    const int w    = t >> 6;        // wave 0..7
    const int wm   = w >> 1;        // 0..3: o-base wm*32
    const int wn   = w & 1;         // 0..1: p-base wn*64

    if (t < COUT) {
        float sc = bn_g[t] * rsqrtf(bn_v[t] + 1e-5f);
        bnss[t]        = sc;
        bnss[t + COUT] = bn_b[t] - bn_m[t] * sc;
    }

    // ---- X staging geometry
    const int pl = full ? (t & 127) : (t & 63);
    const int kg = full ? (t >> 7) : (t >> 6);       // 0..3 (full) / 0..7 (tail)
    const float* xb = x + ((size_t)b * CIN) * NP + p0 + pl;
    const int xrow  = pl * 128;
    const int xswz  = (pl & 7) << 4;

    // ---- W staging geometry: thread t stages o=t>>2, 16 bf16 at k=(t&3)*16
    const int ow = t >> 2, kq = t & 3;
    const ushort* wsrc = wb + ow * CIN + kq * 16;
    const int wbyte0 = ow * 128 + ((kq * 32) ^ ((ow & 7) << 4));
    const int wbyte1 = ow * 128 + ((kq * 32 + 16) ^ ((ow & 7) << 4));

    f32x4 acc[2][4];
#pragma unroll
    for (int mf = 0; mf < 2; ++mf)
#pragma unroll
        for (int nf = 0; nf < 4; ++nf) acc[mf][nf] = (f32x4){0.f, 0.f, 0.f, 0.f};

    float ldx[2][16];   // dist-2 X prefetch (tail blocks use [0..7])
    uint4 ldw0, ldw1;   // dist-1 W prefetch

    // ---- prologue: issue X tiles 0,1; W tile 0; write X0, W0
    if (full) {
#pragma unroll
        for (int j = 0; j < 8; ++j) {
            ldx[0][j]     = xb[(kg * 8 + j) * NP];
            ldx[0][8 + j] = xb[(kg * 8 + 32 + j) * NP];
            ldx[1][j]     = xb[(64 + kg * 8 + j) * NP];
            ldx[1][8 + j] = xb[(64 + kg * 8 + 32 + j) * NP];
        }
    } else {
#pragma unroll
        for (int j = 0; j < 8; ++j) {
            ldx[0][j] = xb[(kg * 8 + j) * NP];
            ldx[1][j] = xb[(64 + kg * 8 + j) * NP];
        }
    }
    ldw0 = *(const uint4*)(wsrc);
    ldw1 = *(const uint4*)(wsrc + 8);
    {
        bf16x8 v8;
#pragma unroll
        for (int j = 0; j < 8; ++j) v8[j] = (__bf16)ldx[0][j];
        *(bf16x8*)((char*)Xs[0] + xrow + ((kg * 16) ^ xswz)) = v8;
        if (full) {
#pragma unroll
            for (int j = 0; j < 8; ++j) v8[j] = (__bf16)ldx[0][8 + j];
            *(bf16x8*)((char*)Xs[0] + xrow + ((kg * 16 + 64) ^ xswz)) = v8;
        }
        *(uint4*)((char*)Ws[0] + wbyte0) = ldw0;
        *(uint4*)((char*)Ws[0] + wbyte1) = ldw1;
    }

#pragma unroll
    for (int kc = 0; kc < 8; ++kc) {
        lds_barrier();
        // issue X tile kc+2 (dist-2)
        if (kc < 6) {
            if (full) {
#pragma unroll
                for (int j = 0; j < 8; ++j) {
                    ldx[kc & 1][j]     = xb[((kc + 2) * 64 + kg * 8 + j) * NP];
                    ldx[kc & 1][8 + j] = xb[((kc + 2) * 64 + kg * 8 + 32 + j) * NP];
                }
            } else {
#pragma unroll
                for (int j = 0; j < 8; ++j)
                    ldx[kc & 1][j] = xb[((kc + 2) * 64 + kg * 8 + j) * NP];
            }
        }
        // issue W tile kc+1 (dist-1, L2-hot)
        if (kc < 7) {
            ldw0 = *(const uint4*)(wsrc + (kc + 1) * 64);
            ldw1 = *(const uint4*)(wsrc + (kc + 1) * 64 + 8);
        }
        // compute tile kc
#pragma unroll
        for (int ks = 0; ks < 2; ++ks) {
            bf16x8 af[2], bfr[4];
#pragma unroll
            for (int mf = 0; mf < 2; ++mf) {
                int o = wm * 32 + mf * 16 + l15;
                af[mf] = *(const bf16x8*)((const char*)Ws[kc & 1]
                          + o * 128 + ((ks * 64 + lg * 16) ^ ((o & 7) << 4)));
            }
#pragma unroll
            for (int nf = 0; nf < 4; ++nf) {
                int p = wn * 64 + nf * 16 + l15;
                bfr[nf] = *(const bf16x8*)((const char*)Xs[kc & 1]
                          + p * 128 + ((ks * 64 + lg * 16) ^ ((p & 7) << 4)));
            }
#pragma unroll
            for (int mf = 0; mf < 2; ++mf)
#pragma unroll
                for (int nf = 0; nf < 4; ++nf)
                    acc[mf][nf] = __builtin_amdgcn_mfma_f32_16x16x32_bf16(
                        af[mf], bfr[nf], acc[mf][nf], 0, 0, 0);
        }
        // write-late: X tile kc+1, W tile kc+1
        if (kc < 7) {
            bf16x8 v8;
#pragma unroll
            for (int j = 0; j < 8; ++j) v8[j] = (__bf16)ldx[(kc + 1) & 1][j];
            *(bf16x8*)((char*)Xs[(kc + 1) & 1] + xrow + ((kg * 16) ^ xswz)) = v8;
            if (full) {
#pragma unroll
                for (int j = 0; j < 8; ++j) v8[j] = (__bf16)ldx[(kc + 1) & 1][8 + j];
                *(bf16x8*)((char*)Xs[(kc + 1) & 1] + xrow + ((kg * 16 + 64) ^ xswz)) = v8;
            }
            *(uint4*)((char*)Ws[(kc + 1) & 1] + wbyte0) = ldw0;
            *(uint4*)((char*)Ws[(kc + 1) & 1] + wbyte1) = ldw1;
        }
    }

    // ---- epilogue: BN + SiLU, sum/max atomics; h staged in LDS, coalesced store
    __syncthreads();
    ushort* Hs = (ushort*)Xs;   // [128 o][128 p] = 32KB overlays X dbuf
    if (full || wn == 0) {
#pragma unroll
        for (int mf = 0; mf < 2; ++mf) {
#pragma unroll
            for (int reg = 0; reg < 4; ++reg) {
                int o = wm * 32 + mf * 16 + lg * 4 + reg;
                float sc = bnss[o], sh = bnss[o + COUT];
                float s_ = 0.f, m_ = -1e30f;
#pragma unroll
                for (int nf = 0; nf < 4; ++nf) {
                    float d    = acc[mf][nf][reg];
                    float hval = d * sc + sh;
                    hval       = hval / (1.f + __expf(-hval));
                    s_ += hval;
                    m_ = fmaxf(m_, hval);
                    __bf16 hb = (__bf16)hval;
                    Hs[o * 128 + wn * 64 + nf * 16 + l15] = *(ushort*)&hb;
                }
#pragma unroll
                for (int d = 1; d < 16; d <<= 1) {
                    s_ += __shfl_xor(s_, d, 64);
                    m_ = fmaxf(m_, __shfl_xor(m_, d, 64));
                }
                if (l15 == 0) {
                    atomicAdd(&sumh[b * COUT + o], s_);
                    atomicMax(&mxenc[b * COUT + o], fenc(m_));
                }
            }
        }
    }
    __syncthreads();
    if (full) {
#pragma unroll
        for (int r = 0; r < 4; ++r) {
            int flat = r * 512 + t;
            int orow = flat >> 4, c = flat & 15;
            uint4 v = *(const uint4*)&Hs[orow * 128 + c * 8];
            *(uint4*)&hout[((size_t)b * COUT + orow) * NP + p0 + c * 8] = v;
        }
    } else {
#pragma unroll
        for (int r = 0; r < 2; ++r) {
            int flat = r * 512 + t;
            int orow = flat >> 3, c = flat & 7;
            uint4 v = *(const uint4*)&Hs[orow * 128 + c * 8];
            *(uint4*)&hout[((size_t)b * COUT + orow) * NP + p0 + c * 8] = v;
        }
    }
}

// ---------------------------------------------------------------------------
// Kernel 2: spatial stats of (h * ca). Computes the channel-attention MLP
// inline; block x==0 publishes ca for k_wsum. sbuf[z][b][{sum,max}][p].
// ---------------------------------------------------------------------------
__global__ __launch_bounds__(256) void k_sstat(const ushort* __restrict__ h,
                                               const float* __restrict__ sumh,
                                               const unsigned* __restrict__ mxenc,
                                               const float* __restrict__ w1,
                                               const float* __restrict__ w2,
                                               float* __restrict__ ca,
                                               float* __restrict__ sbuf)
{
    int b = blockIdx.y, z = blockIdx.z;
    int t = threadIdx.x;
    __shared__ float avg[128], mx[128], r1[16], cas[32];
    if (t < 128) {
        avg[t] = sumh[b * COUT + t] * (1.f / (float)NP);
        mx[t]  = fdec(mxenc[b * COUT + t]);
    }
    __syncthreads();
    if (t < 16) {
        int r = t & 7;
        const float* p = (t < 8) ? avg : mx;
        float s = 0.f;
        for (int c = 0; c < 128; ++c) s += w1[r * 128 + c] * p[c];
        r1[t] = fmaxf(s, 0.f);
    }
    __syncthreads();
    if (t < 32) {
        int o = z * 32 + t;
        float s = 0.f;
#pragma unroll
        for (int r = 0; r < 8; ++r) s += w2[o * 8 + r] * (r1[r] + r1[r + 8]);
        float cv = 1.f / (1.f + __expf(-s));
        cas[t] = cv;
        if (blockIdx.x == 0) ca[b * COUT + o] = cv;
    }
    __syncthreads();

    int pp = blockIdx.x * 256 + t;  // pair index
    if (pp >= NP / 2) return;
    int p = pp * 2;
    const ushort* hb = h + ((size_t)b * COUT + z * 32) * NP + p;
    float s0 = 0.f, s1 = 0.f, m0 = -1e30f, m1 = -1e30f;
#pragma unroll 4
    for (int c = 0; c < 32; ++c) {
        unsigned u = *(const unsigned*)(hb + (size_t)c * NP);
        float cv = cas[c];
        float v0 = bflo(u) * cv;
        float v1 = bfhi(u) * cv;
        s0 += v0; s1 += v1;
        m0 = fmaxf(m0, v0); m1 = fmaxf(m1, v1);
    }
    float* sb = sbuf + ((size_t)(z * NB + b) * 2) * NP;
    sb[p] = s0; sb[p + 1] = s1;
    sb[NP + p] = m0; sb[NP + p + 1] = m1;
}

// ---------------------------------------------------------------------------
// Kernel 3: combine quarters, 7x7 conv (pad 3) + sigmoid -> sigsa[32,3136]
// Row-band parallel: grid (8 bands x NB), each band = 7 rows + 3-row halo.
// ---------------------------------------------------------------------------
__global__ __launch_bounds__(256) void k_conv(const float* __restrict__ sbuf,
                                              const float* __restrict__ saw,
                                              float* __restrict__ sigsa)
{
    int band = blockIdx.x, b = blockIdx.y;
    int y0 = band * 7;
    int t = threadIdx.x;
    __shared__ float s[2][13 * WIMG];
    __shared__ float w[98];
    if (t < 98) w[t] = saw[t];
    for (int i = t; i < 13 * WIMG; i += 256) {
        int yy = y0 - 3 + i / WIMG;
        float vs = 0.f, vm = 0.f;
        if (yy >= 0 && yy < WIMG) {
            int p = yy * WIMG + (i % WIMG);
            float ssum = 0.f, smax = -1e30f;
#pragma unroll
            for (int z = 0; z < 4; ++z) {
                const float* sb = sbuf + ((size_t)(z * NB + b) * 2) * NP;
                ssum += sb[p];
                smax = fmaxf(smax, sb[NP + p]);
            }
            vs = ssum * (1.f / (float)COUT);
            vm = smax;
        }
        s[0][i] = vs;
        s[1][i] = vm;
    }
    __syncthreads();
    for (int i = t; i < 7 * WIMG; i += 256) {
        int ly = i / WIMG, px = i % WIMG;
        float a = 0.f;
#pragma unroll
        for (int ch = 0; ch < 2; ++ch) {
#pragma unroll
            for (int dy = 0; dy < 7; ++dy) {
                int li = (ly + dy) * WIMG;
                for (int dx = 0; dx < 7; ++dx) {
                    int xx = px + dx - 3;
                    if (xx < 0 || xx >= WIMG) continue;
                    a += s[ch][li + xx] * w[ch * 49 + dy * 7 + dx];
                }
            }
        }
        sigsa[b * NP + (y0 + ly) * WIMG + px] = 1.f / (1.f + __expf(-a));
    }
}

// ---------------------------------------------------------------------------
// Kernel 4: t = sum_p h * sigsa ; y = (sum_h + ca*t)/P.  One block per (b,o).
// ---------------------------------------------------------------------------
__global__ __launch_bounds__(256) void k_wsum(const ushort* __restrict__ h,
                                              const float* __restrict__ sigsa,
                                              const float* __restrict__ sumh,
                                              const float* __restrict__ ca,
                                              float* __restrict__ y)
{
    int bo = blockIdx.x;          // b*128+o
    int b = bo >> 7;
    int t = threadIdx.x;
    const ushort* hr = h + (size_t)bo * NP;
    const float* sg  = sigsa + (size_t)b * NP;
    float s = 0.f;
#pragma unroll
    for (int i = 0; i < 3; ++i) {
        int q = (i * 256 + t) * 4;
        uint2 u = *(const uint2*)(hr + q);
        float4 g = *(const float4*)(sg + q);
        s += bflo(u.x) * g.x + bfhi(u.x) * g.y + bflo(u.y) * g.z + bfhi(u.y) * g.w;
    }
    if (t < 16) {
        int q = (768 + t) * 4;
        uint2 u = *(const uint2*)(hr + q);
        float4 g = *(const float4*)(sg + q);
        s += bflo(u.x) * g.x + bfhi(u.x) * g.y + bflo(u.y) * g.z + bfhi(u.y) * g.w;
    }
#pragma unroll
    for (int d = 1; d < 64; d <<= 1) s += __shfl_xor(s, d, 64);
    __shared__ float part[4];
    if ((t & 63) == 0) part[t >> 6] = s;
    __syncthreads();
    if (t == 0) {
        float tt = part[0] + part[1] + part[2] + part[3];
        y[bo] = (sumh[bo] + ca[bo] * tt) * (1.f / (float)NP);
    }
}

// ---------------------------------------------------------------------------
// Kernel 5: LayerNorm over channels -> out[32,128]
// ---------------------------------------------------------------------------
__global__ void k_ln(const float* __restrict__ y, const float* __restrict__ g,
                     const float* __restrict__ bta, float* __restrict__ out)
{
    int b = blockIdx.x, t = threadIdx.x;  // 128 threads
    __shared__ float pr[2], pr2[2];
    float v = y[b * COUT + t];
    float s = v;
#pragma unroll
    for (int d = 1; d < 64; d <<= 1) s += __shfl_xor(s, d, 64);
    if ((t & 63) == 0) pr[t >> 6] = s;
    __syncthreads();
    float mu = (pr[0] + pr[1]) * (1.f / (float)COUT);
    float dv = v - mu;
    float q = dv * dv;
#pragma unroll
    for (int d = 1; d < 64; d <<= 1) q += __shfl_xor(q, d, 64);
    if ((t & 63) == 0) pr2[t >> 6] = q;
    __syncthreads();
    float var = (pr2[0] + pr2[1]) * (1.f / (float)COUT);
    out[b * COUT + t] = dv * rsqrtf(var + 1e-5f) * g[t] + bta[t];
}

// ---------------------------------------------------------------------------
extern "C" void kernel_launch(void* const* d_in, const int* in_sizes, int n_in,
                              void* d_out, int out_size, void* d_ws, size_t ws_size,
                              hipStream_t stream)
{
    const float* x     = (const float*)d_in[0];
    const float* wp    = (const float*)d_in[1];
    const float* bn_g  = (const float*)d_in[2];
    const float* bn_b  = (const float*)d_in[3];
    const float* bn_m  = (const float*)d_in[4];
    const float* bn_v  = (const float*)d_in[5];
    const float* ca_w1 = (const float*)d_in[6];
    const float* ca_w2 = (const float*)d_in[7];
    const float* sa_w  = (const float*)d_in[8];
    const float* ln_g  = (const float*)d_in[9];
    const float* ln_b  = (const float*)d_in[10];
    float* out = (float*)d_out;

    char* ws = (char*)d_ws;
    size_t off = 0;
    ushort*   hbuf  = (ushort*)(ws + off);   off += (size_t)NB * COUT * NP * 2;  // 25.7 MB
    float*    sumh  = (float*)(ws + off);    off += NB * COUT * 4;               // 16 KB
    unsigned* mxenc = (unsigned*)(ws + off); off += NB * COUT * 4;               // 16 KB
    float*    ca    = (float*)(ws + off);    off += NB * COUT * 4;               // 16 KB
    float*    sbuf  = (float*)(ws + off);    off += (size_t)4 * NB * 2 * NP * 4; // 3.2 MB
    float*    sigsa = (float*)(ws + off);    off += (size_t)NB * NP * 4;         // 0.4 MB
    float*    ybuf  = (float*)(ws + off);    off += NB * COUT * 4;
    ushort*   wb16  = (ushort*)(ws + off);   off += (size_t)COUT * CIN * 2;      // 128 KB

    k_wcvt<<<64, 256, 0, stream>>>(wp, wb16, (unsigned*)sumh);
    k_main<<<NB * 25, 512, 0, stream>>>(x, wb16, bn_g, bn_b, bn_m, bn_v, hbuf, sumh, mxenc);
    k_sstat<<<dim3(7, NB, 4), 256, 0, stream>>>(hbuf, sumh, mxenc, ca_w1, ca_w2, ca, sbuf);
    k_conv<<<dim3(8, NB), 256, 0, stream>>>(sbuf, sa_w, sigsa);
    k_wsum<<<NB * COUT, 256, 0, stream>>>(hbuf, sigsa, sumh, ca, ybuf);
    k_ln<<<NB, 128, 0, stream>>>(ybuf, ln_g, ln_b, out);
}

// Round 10
// 80.845 us; speedup vs baseline: 1.6922x; 1.0389x over previous
//
#include <hip/hip_runtime.h>
#include <hip/hip_bf16.h>

typedef __bf16 bf16x8 __attribute__((ext_vector_type(8)));
typedef float f32x4 __attribute__((ext_vector_type(4)));

#define NB 32
#define CIN 512
#define COUT 128
#define NP 3136   // 56*56
#define WIMG 56

__device__ __forceinline__ unsigned fenc(float f) {
    unsigned u = __float_as_uint(f);
    return (u & 0x80000000u) ? ~u : (u | 0x80000000u);
}
__device__ __forceinline__ float fdec(unsigned e) {
    unsigned u = (e & 0x80000000u) ? (e ^ 0x80000000u) : ~e;
    return __uint_as_float(u);
}
__device__ __forceinline__ float bflo(unsigned u) { return __uint_as_float(u << 16); }
__device__ __forceinline__ float bfhi(unsigned u) { return __uint_as_float(u & 0xffff0000u); }

// Relaxed barrier: LDS-visibility only, no vmcnt drain (keep prefetch in flight).
__device__ __forceinline__ void lds_barrier() {
    asm volatile("s_waitcnt lgkmcnt(0)" ::: "memory");
    __builtin_amdgcn_s_barrier();
    __builtin_amdgcn_sched_barrier(0);
}

// ---------------------------------------------------------------------------
// Kernel 0: W f32 -> bf16, plus zero-init of sumh/mxenc.
// ---------------------------------------------------------------------------
__global__ __launch_bounds__(256) void k_wcvt(const float* __restrict__ wp,
                                              ushort* __restrict__ wb,
                                              unsigned* __restrict__ zero8k)
{
    int i = blockIdx.x * 256 + threadIdx.x;   // 16384 threads, 4 elems each
    if (i < 2 * NB * COUT) zero8k[i] = 0u;
    float4 f = *(const float4*)(wp + i * 4);
    ushort4 u;
    __bf16 b0 = (__bf16)f.x, b1 = (__bf16)f.y, b2 = (__bf16)f.z, b3 = (__bf16)f.w;
    u.x = *(ushort*)&b0; u.y = *(ushort*)&b1; u.z = *(ushort*)&b2; u.w = *(ushort*)&b3;
    *(ushort4*)(wb + i * 4) = u;
}

// ---------------------------------------------------------------------------
// Kernel 1: GEMM + BN + SiLU + h store + per-(b,o) sum/max.
// BM=128, BN=64, 1568 blocks, 512 threads (8 waves; wave w owns o-rows
// w*16..+15 across all 64 p). W AND X staged in LDS double-buffers
// (Ws 32KB, Xs 16KB, total 49KB -> 3 blocks/CU = 24 waves/CU, the R10
// occupancy lever). launch_bounds(512,6) caps VGPR at 85 (est. ~70).
// ---------------------------------------------------------------------------
__global__ __launch_bounds__(512, 6) void k_main(
    const float* __restrict__ x, const ushort* __restrict__ wb,
    const float* __restrict__ bn_g, const float* __restrict__ bn_b,
    const float* __restrict__ bn_m, const float* __restrict__ bn_v,
    ushort* __restrict__ hout, float* __restrict__ sumh, unsigned* __restrict__ mxenc)
{
    __shared__ __align__(16) ushort Xs[2][64 * 64];   // 8KB each; epilogue h-tile
    __shared__ __align__(16) ushort Ws[2][128 * 64];  // 16KB each
    __shared__ float bnss[256];

    const int bid  = blockIdx.x;                    // 0..1567, 1568 % 8 == 0
    const int swz  = (bid & 7) * 196 + (bid >> 3);  // bijective XCD swizzle
    const int t    = threadIdx.x;
    const int b    = swz / 49;
    const int p0   = (swz % 49) * 64;
    const int lane = t & 63;
    const int l15  = lane & 15;
    const int lg   = lane >> 4;     // 0..3
    const int w    = t >> 6;        // wave 0..7 -> o-rows w*16..+15

    if (t < COUT) {
        float sc = bn_g[t] * rsqrtf(bn_v[t] + 1e-5f);
        bnss[t]        = sc;
        bnss[t + COUT] = bn_b[t] - bn_m[t] * sc;
    }

    // ---- X staging: thread stages row p=t&63, k-octet kg=t>>6
    const int pr = t & 63;
    const int kg = t >> 6;
    const float* xb = x + ((size_t)b * CIN) * NP + p0 + pr;
    const int xbyte = pr * 128 + ((kg * 16) ^ ((pr & 7) << 4));

    // ---- W staging: thread t stages o=t>>2, 16 bf16 at k=(t&3)*16
    const int ow = t >> 2, kq = t & 3;
    const ushort* wsrc = wb + ow * CIN + kq * 16;
    const int wbyte0 = ow * 128 + ((kq * 32) ^ ((ow & 7) << 4));
    const int wbyte1 = ow * 128 + ((kq * 32 + 16) ^ ((ow & 7) << 4));

    f32x4 acc[4];
#pragma unroll
    for (int nf = 0; nf < 4; ++nf) acc[nf] = (f32x4){0.f, 0.f, 0.f, 0.f};

    float ldx[2][8];    // dist-2 X prefetch
    uint4 ldw0, ldw1;   // dist-1 W prefetch (L2-hot)

    // ---- prologue: issue X tiles 0,1; W tile 0; write X0, W0
#pragma unroll
    for (int j = 0; j < 8; ++j) {
        ldx[0][j] = xb[(kg * 8 + j) * NP];
        ldx[1][j] = xb[(64 + kg * 8 + j) * NP];
    }
    ldw0 = *(const uint4*)(wsrc);
    ldw1 = *(const uint4*)(wsrc + 8);
    {
        bf16x8 v8;
#pragma unroll
        for (int j = 0; j < 8; ++j) v8[j] = (__bf16)ldx[0][j];
        *(bf16x8*)((char*)Xs[0] + xbyte) = v8;
        *(uint4*)((char*)Ws[0] + wbyte0) = ldw0;
        *(uint4*)((char*)Ws[0] + wbyte1) = ldw1;
    }

#pragma unroll
    for (int kc = 0; kc < 8; ++kc) {
        lds_barrier();
        // issue X tile kc+2 (dist-2)
        if (kc < 6) {
#pragma unroll
            for (int j = 0; j < 8; ++j)
                ldx[kc & 1][j] = xb[((kc + 2) * 64 + kg * 8 + j) * NP];
        }
        // issue W tile kc+1 (dist-1)
        if (kc < 7) {
            ldw0 = *(const uint4*)(wsrc + (kc + 1) * 64);
            ldw1 = *(const uint4*)(wsrc + (kc + 1) * 64 + 8);
        }
        // compute tile kc
#pragma unroll
        for (int ks = 0; ks < 2; ++ks) {
            int o = w * 16 + l15;
            bf16x8 af = *(const bf16x8*)((const char*)Ws[kc & 1]
                         + o * 128 + ((ks * 64 + lg * 16) ^ ((o & 7) << 4)));
#pragma unroll
            for (int nf = 0; nf < 4; ++nf) {
                int p = nf * 16 + l15;
                bf16x8 bfr = *(const bf16x8*)((const char*)Xs[kc & 1]
                              + p * 128 + ((ks * 64 + lg * 16) ^ ((p & 7) << 4)));
                acc[nf] = __builtin_amdgcn_mfma_f32_16x16x32_bf16(
                    af, bfr, acc[nf], 0, 0, 0);
            }
        }
        // write-late: X tile kc+1, W tile kc+1
        if (kc < 7) {
            bf16x8 v8;
#pragma unroll
            for (int j = 0; j < 8; ++j) v8[j] = (__bf16)ldx[(kc + 1) & 1][j];
            *(bf16x8*)((char*)Xs[(kc + 1) & 1] + xbyte) = v8;
            *(uint4*)((char*)Ws[(kc + 1) & 1] + wbyte0) = ldw0;
            *(uint4*)((char*)Ws[(kc + 1) & 1] + wbyte1) = ldw1;
        }
    }

    // ---- epilogue: BN + SiLU, sum/max atomics; h staged in LDS, coalesced store
    __syncthreads();
    ushort* Hs = (ushort*)Xs;   // [128 o][64 p] = 16KB overlays X dbuf
#pragma unroll
    for (int reg = 0; reg < 4; ++reg) {
        int o = w * 16 + lg * 4 + reg;
        float sc = bnss[o], sh = bnss[o + COUT];
        float s_ = 0.f, m_ = -1e30f;
#pragma unroll
        for (int nf = 0; nf < 4; ++nf) {
            float d    = acc[nf][reg];
            float hval = d * sc + sh;
            hval       = hval / (1.f + __expf(-hval));
            s_ += hval;
            m_ = fmaxf(m_, hval);
            __bf16 hb = (__bf16)hval;
            Hs[o * 64 + nf * 16 + l15] = *(ushort*)&hb;
        }
#pragma unroll
        for (int d = 1; d < 16; d <<= 1) {
            s_ += __shfl_xor(s_, d, 64);
            m_ = fmaxf(m_, __shfl_xor(m_, d, 64));
        }
        if (l15 == 0) {
            atomicAdd(&sumh[b * COUT + o], s_);
            atomicMax(&mxenc[b * COUT + o], fenc(m_));
        }
    }
    __syncthreads();
#pragma unroll
    for (int r = 0; r < 2; ++r) {
        int flat = r * 512 + t;
        int orow = flat >> 3, c = flat & 7;
        uint4 v = *(const uint4*)&Hs[orow * 64 + c * 8];
        *(uint4*)&hout[((size_t)b * COUT + orow) * NP + p0 + c * 8] = v;
    }
}

// ---------------------------------------------------------------------------
// Kernel 2: spatial stats of (h * ca). Computes the channel-attention MLP
// inline; block x==0 publishes ca for k_wsum. sbuf[z][b][{sum,max}][p].
// ---------------------------------------------------------------------------
__global__ __launch_bounds__(256) void k_sstat(const ushort* __restrict__ h,
                                               const float* __restrict__ sumh,
                                               const unsigned* __restrict__ mxenc,
                                               const float* __restrict__ w1,
                                               const float* __restrict__ w2,
                                               float* __restrict__ ca,
                                               float* __restrict__ sbuf)
{
    int b = blockIdx.y, z = blockIdx.z;
    int t = threadIdx.x;
    __shared__ float avg[128], mx[128], r1[16], cas[32];
    if (t < 128) {
        avg[t] = sumh[b * COUT + t] * (1.f / (float)NP);
        mx[t]  = fdec(mxenc[b * COUT + t]);
    }
    __syncthreads();
    if (t < 16) {
        int r = t & 7;
        const float* p = (t < 8) ? avg : mx;
        float s = 0.f;
        for (int c = 0; c < 128; ++c) s += w1[r * 128 + c] * p[c];
        r1[t] = fmaxf(s, 0.f);
    }
    __syncthreads();
    if (t < 32) {
        int o = z * 32 + t;
        float s = 0.f;
#pragma unroll
        for (int r = 0; r < 8; ++r) s += w2[o * 8 + r] * (r1[r] + r1[r + 8]);
        float cv = 1.f / (1.f + __expf(-s));
        cas[t] = cv;
        if (blockIdx.x == 0) ca[b * COUT + o] = cv;
    }
    __syncthreads();

    int pp = blockIdx.x * 256 + t;  // pair index
    if (pp >= NP / 2) return;
    int p = pp * 2;
    const ushort* hb = h + ((size_t)b * COUT + z * 32) * NP + p;
    float s0 = 0.f, s1 = 0.f, m0 = -1e30f, m1 = -1e30f;
#pragma unroll 4
    for (int c = 0; c < 32; ++c) {
        unsigned u = *(const unsigned*)(hb + (size_t)c * NP);
        float cv = cas[c];
        float v0 = bflo(u) * cv;
        float v1 = bfhi(u) * cv;
        s0 += v0; s1 += v1;
        m0 = fmaxf(m0, v0); m1 = fmaxf(m1, v1);
    }
    float* sb = sbuf + ((size_t)(z * NB + b) * 2) * NP;
    sb[p] = s0; sb[p + 1] = s1;
    sb[NP + p] = m0; sb[NP + p + 1] = m1;
}

// ---------------------------------------------------------------------------
// Kernel 3: combine quarters, 7x7 conv (pad 3) + sigmoid -> sigsa[32,3136]
// Row-band parallel: grid (8 bands x NB), each band = 7 rows + 3-row halo.
// ---------------------------------------------------------------------------
__global__ __launch_bounds__(256) void k_conv(const float* __restrict__ sbuf,
                                              const float* __restrict__ saw,
                                              float* __restrict__ sigsa)
{
    int band = blockIdx.x, b = blockIdx.y;
    int y0 = band * 7;
    int t = threadIdx.x;
    __shared__ float s[2][13 * WIMG];
    __shared__ float w[98];
    if (t < 98) w[t] = saw[t];
    for (int i = t; i < 13 * WIMG; i += 256) {
        int yy = y0 - 3 + i / WIMG;
        float vs = 0.f, vm = 0.f;
        if (yy >= 0 && yy < WIMG) {
            int p = yy * WIMG + (i % WIMG);
            float ssum = 0.f, smax = -1e30f;
#pragma unroll
            for (int z = 0; z < 4; ++z) {
                const float* sb = sbuf + ((size_t)(z * NB + b) * 2) * NP;
                ssum += sb[p];
                smax = fmaxf(smax, sb[NP + p]);
            }
            vs = ssum * (1.f / (float)COUT);
            vm = smax;
        }
        s[0][i] = vs;
        s[1][i] = vm;
    }
    __syncthreads();
    for (int i = t; i < 7 * WIMG; i += 256) {
        int ly = i / WIMG, px = i % WIMG;
        float a = 0.f;
#pragma unroll
        for (int ch = 0; ch < 2; ++ch) {
#pragma unroll
            for (int dy = 0; dy < 7; ++dy) {
                int li = (ly + dy) * WIMG;
                for (int dx = 0; dx < 7; ++dx) {
                    int xx = px + dx - 3;
                    if (xx < 0 || xx >= WIMG) continue;
                    a += s[ch][li + xx] * w[ch * 49 + dy * 7 + dx];
                }
            }
        }
        sigsa[b * NP + (y0 + ly) * WIMG + px] = 1.f / (1.f + __expf(-a));
    }
}

// ---------------------------------------------------------------------------
// Kernel 4: t = sum_p h * sigsa ; y = (sum_h + ca*t)/P.  One block per (b,o).
// ---------------------------------------------------------------------------
__global__ __launch_bounds__(256) void k_wsum(const ushort* __restrict__ h,
                                              const float* __restrict__ sigsa,
                                              const float* __restrict__ sumh,
                                              const float* __restrict__ ca,
                                              float* __restrict__ y)
{
    int bo = blockIdx.x;          // b*128+o
    int b = bo >> 7;
    int t = threadIdx.x;
    const ushort* hr = h + (size_t)bo * NP;
    const float* sg  = sigsa + (size_t)b * NP;
    float s = 0.f;
#pragma unroll
    for (int i = 0; i < 3; ++i) {
        int q = (i * 256 + t) * 4;
        uint2 u = *(const uint2*)(hr + q);
        float4 g = *(const float4*)(sg + q);
        s += bflo(u.x) * g.x + bfhi(u.x) * g.y + bflo(u.y) * g.z + bfhi(u.y) * g.w;
    }
    if (t < 16) {
        int q = (768 + t) * 4;
        uint2 u = *(const uint2*)(hr + q);
        float4 g = *(const float4*)(sg + q);
        s += bflo(u.x) * g.x + bfhi(u.x) * g.y + bflo(u.y) * g.z + bfhi(u.y) * g.w;
    }
#pragma unroll
    for (int d = 1; d < 64; d <<= 1) s += __shfl_xor(s, d, 64);
    __shared__ float part[4];
    if ((t & 63) == 0) part[t >> 6] = s;
    __syncthreads();
    if (t == 0) {
        float tt = part[0] + part[1] + part[2] + part[3];
        y[bo] = (sumh[bo] + ca[bo] * tt) * (1.f / (float)NP);
    }
}

// ---------------------------------------------------------------------------
// Kernel 5: LayerNorm over channels -> out[32,128]
// ---------------------------------------------------------------------------
__global__ void k_ln(const float* __restrict__ y, const float* __restrict__ g,
                     const float* __restrict__ bta, float* __restrict__ out)
{
    int b = blockIdx.x, t = threadIdx.x;  // 128 threads
    __shared__ float pr[2], pr2[2];
    float v = y[b * COUT + t];
    float s = v;
#pragma unroll
    for (int d = 1; d < 64; d <<= 1) s += __shfl_xor(s, d, 64);
    if ((t & 63) == 0) pr[t >> 6] = s;
    __syncthreads();
    float mu = (pr[0] + pr[1]) * (1.f / (float)COUT);
    float dv = v - mu;
    float q = dv * dv;
#pragma unroll
    for (int d = 1; d < 64; d <<= 1) q += __shfl_xor(q, d, 64);
    if ((t & 63) == 0) pr2[t >> 6] = q;
    __syncthreads();
    float var = (pr2[0] + pr2[1]) * (1.f / (float)COUT);
    out[b * COUT + t] = dv * rsqrtf(var + 1e-5f) * g[t] + bta[t];
}

// ---------------------------------------------------------------------------
extern "C" void kernel_launch(void* const* d_in, const int* in_sizes, int n_in,
                              void* d_out, int out_size, void* d_ws, size_t ws_size,
                              hipStream_t stream)
{
    const float* x     = (const float*)d_in[0];
    const float* wp    = (const float*)d_in[1];
    const float* bn_g  = (const float*)d_in[2];
    const float* bn_b  = (const float*)d_in[3];
    const float* bn_m  = (const float*)d_in[4];
    const float* bn_v  = (const float*)d_in[5];
    const float* ca_w1 = (const float*)d_in[6];
    const float* ca_w2 = (const float*)d_in[7];
    const float* sa_w  = (const float*)d_in[8];
    const float* ln_g  = (const float*)d_in[9];
    const float* ln_b  = (const float*)d_in[10];
    float* out = (float*)d_out;

    char* ws = (char*)d_ws;
    size_t off = 0;
    ushort*   hbuf  = (ushort*)(ws + off);   off += (size_t)NB * COUT * NP * 2;  // 25.7 MB
    float*    sumh  = (float*)(ws + off);    off += NB * COUT * 4;               // 16 KB
    unsigned* mxenc = (unsigned*)(ws + off); off += NB * COUT * 4;               // 16 KB
    float*    ca    = (float*)(ws + off);    off += NB * COUT * 4;               // 16 KB
    float*    sbuf  = (float*)(ws + off);    off += (size_t)4 * NB * 2 * NP * 4; // 3.2 MB
    float*    sigsa = (float*)(ws + off);    off += (size_t)NB * NP * 4;         // 0.4 MB
    float*    ybuf  = (float*)(ws + off);    off += NB * COUT * 4;
    ushort*   wb16  = (ushort*)(ws + off);   off += (size_t)COUT * CIN * 2;      // 128 KB

    k_wcvt<<<64, 256, 0, stream>>>(wp, wb16, (unsigned*)sumh);
    k_main<<<NB * 49, 512, 0, stream>>>(x, wb16, bn_g, bn_b, bn_m, bn_v, hbuf, sumh, mxenc);
    k_sstat<<<dim3(7, NB, 4), 256, 0, stream>>>(hbuf, sumh, mxenc, ca_w1, ca_w2, ca, sbuf);
    k_conv<<<dim3(8, NB), 256, 0, stream>>>(sbuf, sa_w, sigsa);
    k_wsum<<<NB * COUT, 256, 0, stream>>>(hbuf, sigsa, sumh, ca, ybuf);
    k_ln<<<NB, 128, 0, stream>>>(ybuf, ln_g, ln_b, out);
}

// Round 11
// 79.725 us; speedup vs baseline: 1.7160x; 1.0140x over previous
//
#include <hip/hip_runtime.h>
#include <hip/hip_bf16.h>

typedef __bf16 bf16x8 __attribute__((ext_vector_type(8)));
typedef float f32x4 __attribute__((ext_vector_type(4)));

#define NB 32
#define CIN 512
#define COUT 128
#define NP 3136   // 56*56
#define WIMG 56

__device__ __forceinline__ unsigned fenc(float f) {
    unsigned u = __float_as_uint(f);
    return (u & 0x80000000u) ? ~u : (u | 0x80000000u);
}
__device__ __forceinline__ float fdec(unsigned e) {
    unsigned u = (e & 0x80000000u) ? (e ^ 0x80000000u) : ~e;
    return __uint_as_float(u);
}
__device__ __forceinline__ float bflo(unsigned u) { return __uint_as_float(u << 16); }
__device__ __forceinline__ float bfhi(unsigned u) { return __uint_as_float(u & 0xffff0000u); }

// two f32 -> two fp8 e4m3 bytes (HW cvt), returned in low 16 bits
__device__ __forceinline__ unsigned cvt2_fp8(float a, float b) {
    unsigned r;
    asm volatile("v_cvt_pk_fp8_f32 %0, %1, %2" : "=&v"(r) : "v"(a), "v"(b));
    return r & 0xffffu;
}
// 4 bf16 (two uints' worth) -> 4 fp8 bytes
__device__ __forceinline__ unsigned pack4_fp8(unsigned u01, unsigned u23) {
    unsigned lo = cvt2_fp8(bflo(u01), bfhi(u01));
    unsigned hi = cvt2_fp8(bflo(u23), bfhi(u23));
    return lo | (hi << 16);
}
// build fp8 e4m3 decode entry for byte v (t in 0..255)
__device__ __forceinline__ float fp8_entry(int v) {
    unsigned s = (v >> 7) & 1, e = (v >> 3) & 15, m = v & 7;
    if (e) return __uint_as_float((s << 31) | ((e + 120) << 23) | (m << 20));
    float f = (float)m * 0x1p-9f;
    return s ? -f : f;
}

// Relaxed barrier: LDS-visibility only, no vmcnt drain.
__device__ __forceinline__ void lds_barrier() {
    asm volatile("s_waitcnt lgkmcnt(0)" ::: "memory");
    __builtin_amdgcn_s_barrier();
    __builtin_amdgcn_sched_barrier(0);
}

// ---------------------------------------------------------------------------
// Kernel 0: W f32 -> bf16, plus zero-init of sumh/mxenc.
// ---------------------------------------------------------------------------
__global__ __launch_bounds__(256) void k_wcvt(const float* __restrict__ wp,
                                              ushort* __restrict__ wb,
                                              unsigned* __restrict__ zero8k)
{
    int i = blockIdx.x * 256 + threadIdx.x;
    if (i < 2 * NB * COUT) zero8k[i] = 0u;
    float4 f = *(const float4*)(wp + i * 4);
    ushort4 u;
    __bf16 b0 = (__bf16)f.x, b1 = (__bf16)f.y, b2 = (__bf16)f.z, b3 = (__bf16)f.w;
    u.x = *(ushort*)&b0; u.y = *(ushort*)&b1; u.z = *(ushort*)&b2; u.w = *(ushort*)&b3;
    *(ushort4*)(wb + i * 4) = u;
}

// ---------------------------------------------------------------------------
// Kernel 1: GEMM + BN + SiLU + h store (fp8) + per-(b,o) sum/max.
// BM=128, BN=64, 1568 blocks, 512 threads, 8 waves as 4M x 2N (mf=2, nf=2:
// 1.0 LDS reads per MFMA). W & X in LDS dbuf (49KB -> 3 blocks/CU).
// Cross-wave LDS combine -> 128 atomic pairs per block. h written as fp8.
// ---------------------------------------------------------------------------
__global__ __launch_bounds__(512, 6) void k_main(
    const float* __restrict__ x, const ushort* __restrict__ wb,
    const float* __restrict__ bn_g, const float* __restrict__ bn_b,
    const float* __restrict__ bn_m, const float* __restrict__ bn_v,
    uchar* __restrict__ hout, float* __restrict__ sumh, unsigned* __restrict__ mxenc)
{
    __shared__ __align__(16) ushort Xs[2][64 * 64];   // 8KB each; epilogue h-tile
    __shared__ __align__(16) ushort Ws[2][128 * 64];  // 16KB each
    __shared__ float bnss[256];
    __shared__ float redS[2][COUT];   // [wn][o] partial sums
    __shared__ float redM[2][COUT];   // [wn][o] partial maxes

    const int bid  = blockIdx.x;                    // 0..1567, 1568 % 8 == 0
    const int swz  = (bid & 7) * 196 + (bid >> 3);  // bijective XCD swizzle
    const int t    = threadIdx.x;
    const int b    = swz / 49;
    const int p0   = (swz % 49) * 64;
    const int lane = t & 63;
    const int l15  = lane & 15;
    const int lg   = lane >> 4;     // 0..3
    const int w    = t >> 6;        // wave 0..7
    const int wm   = w >> 1;        // 0..3: o-base wm*32
    const int wn   = w & 1;         // 0..1: p-base wn*32

    if (t < COUT) {
        float sc = bn_g[t] * rsqrtf(bn_v[t] + 1e-5f);
        bnss[t]        = sc;
        bnss[t + COUT] = bn_b[t] - bn_m[t] * sc;
    }

    // ---- X staging: thread stages row p=t&63, k-octet kg=t>>6
    const int pr = t & 63;
    const int kg = t >> 6;
    const float* xb = x + ((size_t)b * CIN) * NP + p0 + pr;
    const int xbyte = pr * 128 + ((kg * 16) ^ ((pr & 7) << 4));

    // ---- W staging: thread t stages o=t>>2, 16 bf16 at k=(t&3)*16
    const int ow = t >> 2, kq = t & 3;
    const ushort* wsrc = wb + ow * CIN + kq * 16;
    const int wbyte0 = ow * 128 + ((kq * 32) ^ ((ow & 7) << 4));
    const int wbyte1 = ow * 128 + ((kq * 32 + 16) ^ ((ow & 7) << 4));

    f32x4 acc[2][2];
#pragma unroll
    for (int mf = 0; mf < 2; ++mf)
#pragma unroll
        for (int nf = 0; nf < 2; ++nf) acc[mf][nf] = (f32x4){0.f, 0.f, 0.f, 0.f};

    float ldx[2][8];
    uint4 ldw0, ldw1;

    // ---- prologue
#pragma unroll
    for (int j = 0; j < 8; ++j) {
        ldx[0][j] = xb[(kg * 8 + j) * NP];
        ldx[1][j] = xb[(64 + kg * 8 + j) * NP];
    }
    ldw0 = *(const uint4*)(wsrc);
    ldw1 = *(const uint4*)(wsrc + 8);
    {
        bf16x8 v8;
#pragma unroll
        for (int j = 0; j < 8; ++j) v8[j] = (__bf16)ldx[0][j];
        *(bf16x8*)((char*)Xs[0] + xbyte) = v8;
        *(uint4*)((char*)Ws[0] + wbyte0) = ldw0;
        *(uint4*)((char*)Ws[0] + wbyte1) = ldw1;
    }

#pragma unroll
    for (int kc = 0; kc < 8; ++kc) {
        lds_barrier();
        if (kc < 6) {
#pragma unroll
            for (int j = 0; j < 8; ++j)
                ldx[kc & 1][j] = xb[((kc + 2) * 64 + kg * 8 + j) * NP];
        }
        if (kc < 7) {
            ldw0 = *(const uint4*)(wsrc + (kc + 1) * 64);
            ldw1 = *(const uint4*)(wsrc + (kc + 1) * 64 + 8);
        }
#pragma unroll
        for (int ks = 0; ks < 2; ++ks) {
            bf16x8 af[2], bfr[2];
#pragma unroll
            for (int mf = 0; mf < 2; ++mf) {
                int o = wm * 32 + mf * 16 + l15;
                af[mf] = *(const bf16x8*)((const char*)Ws[kc & 1]
                          + o * 128 + ((ks * 64 + lg * 16) ^ ((o & 7) << 4)));
            }
#pragma unroll
            for (int nf = 0; nf < 2; ++nf) {
                int p = wn * 32 + nf * 16 + l15;
                bfr[nf] = *(const bf16x8*)((const char*)Xs[kc & 1]
                           + p * 128 + ((ks * 64 + lg * 16) ^ ((p & 7) << 4)));
            }
#pragma unroll
            for (int mf = 0; mf < 2; ++mf)
#pragma unroll
                for (int nf = 0; nf < 2; ++nf)
                    acc[mf][nf] = __builtin_amdgcn_mfma_f32_16x16x32_bf16(
                        af[mf], bfr[nf], acc[mf][nf], 0, 0, 0);
        }
        if (kc < 7) {
            bf16x8 v8;
#pragma unroll
            for (int j = 0; j < 8; ++j) v8[j] = (__bf16)ldx[(kc + 1) & 1][j];
            *(bf16x8*)((char*)Xs[(kc + 1) & 1] + xbyte) = v8;
            *(uint4*)((char*)Ws[(kc + 1) & 1] + wbyte0) = ldw0;
            *(uint4*)((char*)Ws[(kc + 1) & 1] + wbyte1) = ldw1;
        }
    }

    // ---- epilogue: BN + SiLU, stage h (bf16) in LDS, per-(wn,o) partials
    __syncthreads();                 // all Xs reads done before reuse
    ushort* Hs = (ushort*)Xs;        // [128 o][64 p] ushort = 16KB
#pragma unroll
    for (int mf = 0; mf < 2; ++mf) {
#pragma unroll
        for (int reg = 0; reg < 4; ++reg) {
            int o = wm * 32 + mf * 16 + lg * 4 + reg;
            float sc = bnss[o], sh = bnss[o + COUT];
            float s_ = 0.f, m_ = -1e30f;
#pragma unroll
            for (int nf = 0; nf < 2; ++nf) {
                float d    = acc[mf][nf][reg];
                float hval = d * sc + sh;
                hval       = hval / (1.f + __expf(-hval));
                s_ += hval;
                m_ = fmaxf(m_, hval);
                __bf16 hb = (__bf16)hval;
                Hs[o * 64 + wn * 32 + nf * 16 + l15] = *(ushort*)&hb;
            }
#pragma unroll
            for (int d = 1; d < 16; d <<= 1) {
                s_ += __shfl_xor(s_, d, 64);
                m_ = fmaxf(m_, __shfl_xor(m_, d, 64));
            }
            if (l15 == 0) {
                redS[wn][o] = s_;
                redM[wn][o] = m_;
            }
        }
    }
    __syncthreads();
    if (t < COUT) {
        atomicAdd(&sumh[b * COUT + t], redS[0][t] + redS[1][t]);
        atomicMax(&mxenc[b * COUT + t], fenc(fmaxf(redM[0][t], redM[1][t])));
    }
    // coalesced fp8 h write: thread t -> row t>>2, 16 bytes at (t&3)*16
    {
        int orow = t >> 2, c = t & 3;
        uint4 a  = *(const uint4*)&Hs[orow * 64 + c * 16];
        uint4 b4 = *(const uint4*)&Hs[orow * 64 + c * 16 + 8];
        uint4 o4;
        o4.x = pack4_fp8(a.x, a.y);
        o4.y = pack4_fp8(a.z, a.w);
        o4.z = pack4_fp8(b4.x, b4.y);
        o4.w = pack4_fp8(b4.z, b4.w);
        *(uint4*)&hout[((size_t)b * COUT + orow) * NP + p0 + c * 16] = o4;
    }
}

// ---------------------------------------------------------------------------
// Kernel 2: spatial stats of (h * ca), h in fp8 (LDS decode table).
// Inline ca MLP; block x==0 publishes ca. sbuf[z][b][{sum,max}][p].
// Grid (4, NB, 4); each thread handles 4 positions (one uint).
// ---------------------------------------------------------------------------
__global__ __launch_bounds__(256) void k_sstat(const uchar* __restrict__ h,
                                               const float* __restrict__ sumh,
                                               const unsigned* __restrict__ mxenc,
                                               const float* __restrict__ w1,
                                               const float* __restrict__ w2,
                                               float* __restrict__ ca,
                                               float* __restrict__ sbuf)
{
    int b = blockIdx.y, z = blockIdx.z;
    int t = threadIdx.x;
    __shared__ float avg[128], mx[128], r1[16], cas[32], tab[256];
    tab[t] = fp8_entry(t);
    if (t < 128) {
        avg[t] = sumh[b * COUT + t] * (1.f / (float)NP);
        mx[t]  = fdec(mxenc[b * COUT + t]);
    }
    __syncthreads();
    if (t < 16) {
        int r = t & 7;
        const float* p = (t < 8) ? avg : mx;
        float s = 0.f;
        for (int c = 0; c < 128; ++c) s += w1[r * 128 + c] * p[c];
        r1[t] = fmaxf(s, 0.f);
    }
    __syncthreads();
    if (t < 32) {
        int o = z * 32 + t;
        float s = 0.f;
#pragma unroll
        for (int r = 0; r < 8; ++r) s += w2[o * 8 + r] * (r1[r] + r1[r + 8]);
        float cv = 1.f / (1.f + __expf(-s));
        cas[t] = cv;
        if (blockIdx.x == 0) ca[b * COUT + o] = cv;
    }
    __syncthreads();

    int idx = blockIdx.x * 256 + t;   // quad index
    if (idx >= NP / 4) return;
    int p = idx * 4;
    const uchar* hb = h + ((size_t)(b * COUT + z * 32)) * NP + p;
    float s0 = 0.f, s1 = 0.f, s2 = 0.f, s3 = 0.f;
    float m0 = -1e30f, m1 = -1e30f, m2 = -1e30f, m3 = -1e30f;
#pragma unroll 4
    for (int c = 0; c < 32; ++c) {
        unsigned u = *(const unsigned*)(hb + (size_t)c * NP);
        float cv = cas[c];
        float v0 = tab[u & 255] * cv;
        float v1 = tab[(u >> 8) & 255] * cv;
        float v2 = tab[(u >> 16) & 255] * cv;
        float v3 = tab[u >> 24] * cv;
        s0 += v0; s1 += v1; s2 += v2; s3 += v3;
        m0 = fmaxf(m0, v0); m1 = fmaxf(m1, v1);
        m2 = fmaxf(m2, v2); m3 = fmaxf(m3, v3);
    }
    float* sb = sbuf + ((size_t)(z * NB + b) * 2) * NP;
    *(float4*)&sb[p]      = make_float4(s0, s1, s2, s3);
    *(float4*)&sb[NP + p] = make_float4(m0, m1, m2, m3);
}

// ---------------------------------------------------------------------------
// Kernel 3: combine quarters, 7x7 conv (pad 3) + sigmoid -> sigsa[32,3136]
// ---------------------------------------------------------------------------
__global__ __launch_bounds__(256) void k_conv(const float* __restrict__ sbuf,
                                              const float* __restrict__ saw,
                                              float* __restrict__ sigsa)
{
    int band = blockIdx.x, b = blockIdx.y;
    int y0 = band * 7;
    int t = threadIdx.x;
    __shared__ float s[2][13 * WIMG];
    __shared__ float w[98];
    if (t < 98) w[t] = saw[t];
    for (int i = t; i < 13 * WIMG; i += 256) {
        int yy = y0 - 3 + i / WIMG;
        float vs = 0.f, vm = 0.f;
        if (yy >= 0 && yy < WIMG) {
            int p = yy * WIMG + (i % WIMG);
            float ssum = 0.f, smax = -1e30f;
#pragma unroll
            for (int z = 0; z < 4; ++z) {
                const float* sb = sbuf + ((size_t)(z * NB + b) * 2) * NP;
                ssum += sb[p];
                smax = fmaxf(smax, sb[NP + p]);
            }
            vs = ssum * (1.f / (float)COUT);
            vm = smax;
        }
        s[0][i] = vs;
        s[1][i] = vm;
    }
    __syncthreads();
    for (int i = t; i < 7 * WIMG; i += 256) {
        int ly = i / WIMG, px = i % WIMG;
        float a = 0.f;
#pragma unroll
        for (int ch = 0; ch < 2; ++ch) {
#pragma unroll
            for (int dy = 0; dy < 7; ++dy) {
                int li = (ly + dy) * WIMG;
                for (int dx = 0; dx < 7; ++dx) {
                    int xx = px + dx - 3;
                    if (xx < 0 || xx >= WIMG) continue;
                    a += s[ch][li + xx] * w[ch * 49 + dy * 7 + dx];
                }
            }
        }
        sigsa[b * NP + (y0 + ly) * WIMG + px] = 1.f / (1.f + __expf(-a));
    }
}

// ---------------------------------------------------------------------------
// Kernel 4: t = sum_p h * sigsa ; y = (sum_h + ca*t)/P.  One block per (b,o).
// h in fp8 (LDS decode table).
// ---------------------------------------------------------------------------
__global__ __launch_bounds__(256) void k_wsum(const uchar* __restrict__ h,
                                              const float* __restrict__ sigsa,
                                              const float* __restrict__ sumh,
                                              const float* __restrict__ ca,
                                              float* __restrict__ y)
{
    int bo = blockIdx.x;          // b*128+o
    int b = bo >> 7;
    int t = threadIdx.x;
    __shared__ float tab[256];
    __shared__ float part[4];
    tab[t] = fp8_entry(t);
    __syncthreads();
    const uchar* hr = h + (size_t)bo * NP;
    const float* sg  = sigsa + (size_t)b * NP;
    float s = 0.f;
#pragma unroll
    for (int i = 0; i < 3; ++i) {
        int q = i * 256 + t;       // quad index < 768
        unsigned u = *(const unsigned*)(hr + q * 4);
        float4 g = *(const float4*)(sg + q * 4);
        s += tab[u & 255] * g.x + tab[(u >> 8) & 255] * g.y
           + tab[(u >> 16) & 255] * g.z + tab[u >> 24] * g.w;
    }
    if (t < 16) {
        int q = 768 + t;           // 784 quads total
        unsigned u = *(const unsigned*)(hr + q * 4);
        float4 g = *(const float4*)(sg + q * 4);
        s += tab[u & 255] * g.x + tab[(u >> 8) & 255] * g.y
           + tab[(u >> 16) & 255] * g.z + tab[u >> 24] * g.w;
    }
#pragma unroll
    for (int d = 1; d < 64; d <<= 1) s += __shfl_xor(s, d, 64);
    if ((t & 63) == 0) part[t >> 6] = s;
    __syncthreads();
    if (t == 0) {
        float tt = part[0] + part[1] + part[2] + part[3];
        y[bo] = (sumh[bo] + ca[bo] * tt) * (1.f / (float)NP);
    }
}

// ---------------------------------------------------------------------------
// Kernel 5: LayerNorm over channels -> out[32,128]
// ---------------------------------------------------------------------------
__global__ void k_ln(const float* __restrict__ y, const float* __restrict__ g,
                     const float* __restrict__ bta, float* __restrict__ out)
{
    int b = blockIdx.x, t = threadIdx.x;  // 128 threads
    __shared__ float pr[2], pr2[2];
    float v = y[b * COUT + t];
    float s = v;
#pragma unroll
    for (int d = 1; d < 64; d <<= 1) s += __shfl_xor(s, d, 64);
    if ((t & 63) == 0) pr[t >> 6] = s;
    __syncthreads();
    float mu = (pr[0] + pr[1]) * (1.f / (float)COUT);
    float dv = v - mu;
    float q = dv * dv;
#pragma unroll
    for (int d = 1; d < 64; d <<= 1) q += __shfl_xor(q, d, 64);
    if ((t & 63) == 0) pr2[t >> 6] = q;
    __syncthreads();
    float var = (pr2[0] + pr2[1]) * (1.f / (float)COUT);
    out[b * COUT + t] = dv * rsqrtf(var + 1e-5f) * g[t] + bta[t];
}

// ---------------------------------------------------------------------------
extern "C" void kernel_launch(void* const* d_in, const int* in_sizes, int n_in,
                              void* d_out, int out_size, void* d_ws, size_t ws_size,
                              hipStream_t stream)
{
    const float* x     = (const float*)d_in[0];
    const float* wp    = (const float*)d_in[1];
    const float* bn_g  = (const float*)d_in[2];
    const float* bn_b  = (const float*)d_in[3];
    const float* bn_m  = (const float*)d_in[4];
    const float* bn_v  = (const float*)d_in[5];
    const float* ca_w1 = (const float*)d_in[6];
    const float* ca_w2 = (const float*)d_in[7];
    const float* sa_w  = (const float*)d_in[8];
    const float* ln_g  = (const float*)d_in[9];
    const float* ln_b  = (const float*)d_in[10];
    float* out = (float*)d_out;

    char* ws = (char*)d_ws;
    size_t off = 0;
    uchar*    hbuf  = (uchar*)(ws + off);    off += (size_t)NB * COUT * NP;      // 12.8 MB
    float*    sumh  = (float*)(ws + off);    off += NB * COUT * 4;               // 16 KB
    unsigned* mxenc = (unsigned*)(ws + off); off += NB * COUT * 4;               // 16 KB
    float*    ca    = (float*)(ws + off);    off += NB * COUT * 4;               // 16 KB
    float*    sbuf  = (float*)(ws + off);    off += (size_t)4 * NB * 2 * NP * 4; // 3.2 MB
    float*    sigsa = (float*)(ws + off);    off += (size_t)NB * NP * 4;         // 0.4 MB
    float*    ybuf  = (float*)(ws + off);    off += NB * COUT * 4;
    ushort*   wb16  = (ushort*)(ws + off);   off += (size_t)COUT * CIN * 2;      // 128 KB

    k_wcvt<<<64, 256, 0, stream>>>(wp, wb16, (unsigned*)sumh);
    k_main<<<NB * 49, 512, 0, stream>>>(x, wb16, bn_g, bn_b, bn_m, bn_v, hbuf, sumh, mxenc);
    k_sstat<<<dim3(4, NB, 4), 256, 0, stream>>>(hbuf, sumh, mxenc, ca_w1, ca_w2, ca, sbuf);
    k_conv<<<dim3(8, NB), 256, 0, stream>>>(sbuf, sa_w, sigsa);
    k_wsum<<<NB * COUT, 256, 0, stream>>>(hbuf, sigsa, sumh, ca, ybuf);
    k_ln<<<NB, 128, 0, stream>>>(ybuf, ln_g, ln_b, out);
}